// Round 3
// baseline (1386.409 us; speedup 1.0000x reference)
//
#include <hip/hip_runtime.h>

#define N_NODES 100000
#define N_EDGES 1000000
#define N_GRAPHS 128
#define CH 128          // edges per wave chunk in sorted-edge phase
#define SCAN_T 1024
#define SEG ((N_NODES + SCAN_T - 1) / SCAN_T)   // 98

// ===========================================================================
// Preprocessing: counting-sort edges by dst (rebuilt every call; ws is
// re-poisoned before each launch).
// ===========================================================================
__global__ __launch_bounds__(256) void count_kernel(
    const int* __restrict__ dst, int* __restrict__ counts)
{
    int e = blockIdx.x * blockDim.x + threadIdx.x;
    if (e < N_EDGES) atomicAdd(&counts[dst[e]], 1);
}

// single-block exclusive scan of counts -> cursor (scatter write positions)
__global__ __launch_bounds__(SCAN_T) void scan_kernel(
    const int* __restrict__ counts, int* __restrict__ cursor)
{
    __shared__ int part[SCAN_T];
    const int t = threadIdx.x;
    const int beg = t * SEG;
    const int end = min(beg + SEG, N_NODES);

    int s = 0;
    for (int i = beg; i < end; ++i) s += counts[i];
    part[t] = s;
    __syncthreads();

    for (int off = 1; off < SCAN_T; off <<= 1) {
        int tmp = (t >= off) ? part[t - off] : 0;
        __syncthreads();
        part[t] += tmp;
        __syncthreads();
    }
    int off0 = part[t] - s;  // exclusive prefix of this segment
    for (int i = beg; i < end; ++i) {
        cursor[i] = off0;
        off0 += counts[i];
    }
}

__global__ __launch_bounds__(256) void scatter_kernel(
    const int* __restrict__ src, const int* __restrict__ dst,
    int* __restrict__ cursor,
    int* __restrict__ eids_s, int* __restrict__ src_s, int* __restrict__ dst_s)
{
    int e = blockIdx.x * blockDim.x + threadIdx.x;
    if (e >= N_EDGES) return;
    int d = dst[e];
    int pos = atomicAdd(&cursor[d], 1);
    eids_s[pos] = e;
    src_s[pos]  = src[e];
    dst_s[pos]  = d;
}

// ===========================================================================
// Edge phase on dst-sorted edges: one wave per 128-edge chunk, lane i owns
// feature i. Runs of equal dst accumulate in registers; interior runs get a
// PLAIN STORE (sole writer), chunk-boundary runs atomicAdd into zeroed aggr.
// All indices forced wave-uniform -> scalar loads, scalar-operand FMAs.
// ===========================================================================
__global__ __launch_bounds__(256) void edge_sorted_kernel(
    const float* __restrict__ x,      // [N,64] conv input
    const float* __restrict__ ea,     // [E,32]
    const int*   __restrict__ src_s,  // [E] sorted by dst
    const int*   __restrict__ dst_s,  // [E] sorted (grouped)
    const int*   __restrict__ eids_s, // [E] original edge id
    const float* __restrict__ We,     // [32,64]
    const float* __restrict__ be,     // [64]
    float*       __restrict__ aggr)   // [N,64], pre-zeroed
{
    const int lane = threadIdx.x & 63;
    const int wid  = (blockIdx.x * blockDim.x + threadIdx.x) >> 6;
    const int p0   = __builtin_amdgcn_readfirstlane(wid * CH);
    if (p0 >= N_EDGES) return;
    const int pend = min(p0 + CH, N_EDGES);

    float w[32];
#pragma unroll
    for (int k = 0; k < 32; ++k) w[k] = We[k * 64 + lane];
    const float b = be[lane];

    const int prev_d = (p0 > 0)        ? __builtin_amdgcn_readfirstlane(dst_s[p0 - 1]) : -1;
    const int next_d = (pend < N_EDGES)? __builtin_amdgcn_readfirstlane(dst_s[pend])   : -1;

    int  cur       = __builtin_amdgcn_readfirstlane(dst_s[p0]);
    bool first_run = true;
    float acc = 0.0f;

    for (int p = p0; p < pend; ++p) {
        const int d = __builtin_amdgcn_readfirstlane(dst_s[p]);
        if (d != cur) {
            // flush finished run
            if (first_run && cur == prev_d)
                atomicAdd(&aggr[(size_t)cur * 64 + lane], acc);
            else
                aggr[(size_t)cur * 64 + lane] = acc;   // sole writer
            first_run = false;
            cur = d;
            acc = 0.0f;
        }
        const int e = __builtin_amdgcn_readfirstlane(eids_s[p]);
        const int s = __builtin_amdgcn_readfirstlane(src_s[p]);
        const float* er = ea + (size_t)e * 32;   // uniform 128B row -> s_loads

        float ev = b;
#pragma unroll
        for (int k = 0; k < 32; ++k)
            ev = fmaf(er[k], w[k], ev);

        acc += fmaxf(x[(size_t)s * 64 + lane] + ev, 0.0f);
    }
    // flush last run: shared with next chunk, or spans whole chunk from prev
    if ((cur == next_d) || (first_run && cur == prev_d))
        atomicAdd(&aggr[(size_t)cur * 64 + lane], acc);
    else
        aggr[(size_t)cur * 64 + lane] = acc;
}

// ===========================================================================
// Fallback edge phase (round-2 verified path): wave per edge, full atomics.
// Used only if ws_size is too small for the sort buffers.
// ===========================================================================
__global__ __launch_bounds__(256) void edge_kernel(
    const float* __restrict__ x, const float* __restrict__ ea,
    const int* __restrict__ src, const int* __restrict__ dst,
    const float* __restrict__ We, const float* __restrict__ be,
    float* __restrict__ aggr)
{
    const int lane = threadIdx.x & 63;
    const int wid  = (blockIdx.x * blockDim.x + threadIdx.x) >> 6;
    const int nw   = (gridDim.x * blockDim.x) >> 6;

    float w[32];
#pragma unroll
    for (int k = 0; k < 32; ++k) w[k] = We[k * 64 + lane];
    const float b = be[lane];

    const int e0 = __builtin_amdgcn_readfirstlane(wid);
    for (int e = e0; e < N_EDGES; e += nw) {
        const int s = src[e];
        const int d = dst[e];
        const float* earow = ea + (size_t)e * 32;
        const float xv = x[(size_t)s * 64 + lane];
        float acc = b;
#pragma unroll
        for (int k = 0; k < 32; ++k)
            acc = fmaf(earow[k], w[k], acc);
        const float m = fmaxf(xv + acc, 0.0f);
        atomicAdd(&aggr[(size_t)d * 64 + lane], m);
    }
}

// ===========================================================================
// Node phase: wave per node, lane i owns feature i.
//   out = relu( relu(((1+eps)x+aggr)@W1+b1) @ W2 + b2 )
// ===========================================================================
__global__ __launch_bounds__(256) void node_kernel(
    const float* __restrict__ x_in, const float* __restrict__ aggr,
    const float* __restrict__ eps,
    const float* __restrict__ W1, const float* __restrict__ b1,
    const float* __restrict__ W2, const float* __restrict__ b2,
    float* __restrict__ h_out)
{
    const int lane = threadIdx.x & 63;
    const int wid  = (blockIdx.x * blockDim.x + threadIdx.x) >> 6;
    const int nw   = (gridDim.x * blockDim.x) >> 6;

    float w1[64], w2[64];
#pragma unroll
    for (int i = 0; i < 64; ++i) w1[i] = W1[i * 64 + lane];
#pragma unroll
    for (int i = 0; i < 64; ++i) w2[i] = W2[i * 64 + lane];
    const float b1v = b1[lane];
    const float b2v = b2[lane];
    const float ep  = 1.0f + eps[0];

    for (int n = wid; n < N_NODES; n += nw) {
        const size_t base = (size_t)n * 64;
        const float h = fmaf(ep, x_in[base + lane], aggr[base + lane]);

        float t = b1v;
#pragma unroll
        for (int i = 0; i < 64; ++i)
            t = fmaf(__shfl(h, i), w1[i], t);
        t = fmaxf(t, 0.0f);

        float o = b2v;
#pragma unroll
        for (int i = 0; i < 64; ++i)
            o = fmaf(__shfl(t, i), w2[i], o);

        h_out[base + lane] = fmaxf(o, 0.0f);
    }
}

// ===========================================================================
// Pooling (batch sorted): wave per 128-node chunk, atomic per graph-run.
// ===========================================================================
#define POOL_CHUNK 128
__global__ __launch_bounds__(256) void pool_kernel(
    const float* __restrict__ h, const int* __restrict__ batch,
    float* __restrict__ pooled)
{
    const int lane  = threadIdx.x & 63;
    const int wid   = (blockIdx.x * blockDim.x + threadIdx.x) >> 6;
    const int start = wid * POOL_CHUNK;
    if (start >= N_NODES) return;
    const int end = min(start + POOL_CHUNK, N_NODES);

    int   gcur = batch[start];
    float acc  = 0.0f;
    for (int n = start; n < end; ++n) {
        const int g = batch[n];
        if (g != gcur) {
            atomicAdd(&pooled[gcur * 64 + lane], acc);
            acc  = 0.0f;
            gcur = g;
        }
        acc += h[(size_t)n * 64 + lane];
    }
    atomicAdd(&pooled[gcur * 64 + lane], acc);
}

// ===========================================================================
// Head: one block (128 threads) per graph.
// ===========================================================================
__global__ __launch_bounds__(128) void head_kernel(
    const float* __restrict__ pooled, const float* __restrict__ Wf1,
    const float* __restrict__ bf1, const float* __restrict__ Wf2,
    const float* __restrict__ bf2, float* __restrict__ out)
{
    __shared__ float p[64];
    __shared__ float red[2];
    const int g = blockIdx.x;
    const int j = threadIdx.x;

    if (j < 64) p[j] = pooled[g * 64 + j];
    __syncthreads();

    float t = bf1[j];
#pragma unroll
    for (int i = 0; i < 64; ++i)
        t = fmaf(p[i], Wf1[i * 128 + j], t);
    t = fmaxf(t, 0.0f);

    float v = t * Wf2[j];
    for (int off = 32; off > 0; off >>= 1)
        v += __shfl_down(v, off);
    if ((j & 63) == 0) red[j >> 6] = v;
    __syncthreads();
    if (j == 0) out[g] = red[0] + red[1] + bf2[0];
}

extern "C" void kernel_launch(void* const* d_in, const int* in_sizes, int n_in,
                              void* d_out, int out_size, void* d_ws, size_t ws_size,
                              hipStream_t stream) {
    const float* x    = (const float*)d_in[0];
    const float* ea   = (const float*)d_in[1];
    const int*   esrc = (const int*)  d_in[2];
    const int*   edst = (const int*)  d_in[3];
    const int*   batch= (const int*)  d_in[4];
    const float* eps1 = (const float*)d_in[5];
    const float* We1  = (const float*)d_in[6];
    const float* be1  = (const float*)d_in[7];
    const float* W11  = (const float*)d_in[8];
    const float* b11  = (const float*)d_in[9];
    const float* W12  = (const float*)d_in[10];
    const float* b12  = (const float*)d_in[11];
    const float* eps2 = (const float*)d_in[12];
    const float* We2  = (const float*)d_in[13];
    const float* be2  = (const float*)d_in[14];
    const float* W21  = (const float*)d_in[15];
    const float* b21  = (const float*)d_in[16];
    const float* W22  = (const float*)d_in[17];
    const float* b22  = (const float*)d_in[18];
    const float* Wf1  = (const float*)d_in[19];
    const float* bf1  = (const float*)d_in[20];
    const float* Wf2  = (const float*)d_in[21];
    const float* bf2  = (const float*)d_in[22];
    float* out = (float*)d_out;

    // ---- workspace layout (all region starts 256B-aligned) ----
    const size_t NF = (size_t)N_NODES * 64 * sizeof(float);  // 25,600,000
    char* ws = (char*)d_ws;
    float* aggr   = (float*)ws;                    // 25.6 MB
    float* h      = (float*)(ws + NF);             // 25.6 MB
    float* pooled = (float*)(ws + 2 * NF);         // 32 KB
    char*  p4     = ws + 2 * NF + 32768;
    int* counts = (int*)p4;                        // 409,600 B
    int* cursor = (int*)(p4 + 409600);             // 409,600 B
    int* eids_s = (int*)(p4 + 2 * 409600);         // 4,000,000 B
    int* src_s  = (int*)(p4 + 2 * 409600 + 4000000);
    int* dst_s  = (int*)(p4 + 2 * 409600 + 8000000);
    const size_t need = 2 * NF + 32768 + 2 * 409600 + 12000000;

    const int NODE_BLOCKS = 1024;
    const int POOL_BLOCKS = ((N_NODES + POOL_CHUNK - 1) / POOL_CHUNK + 3) / 4;
    const int E_TH_BLOCKS = (N_EDGES + 255) / 256;                  // 3907
    const int CHUNK_WAVES = (N_EDGES + CH - 1) / CH;                // 7813
    const int CHUNK_BLOCKS= (CHUNK_WAVES + 3) / 4;                  // 1954

    if (ws_size >= need) {
        // ---- build dst-sorted edge list (once; reused by both convs) ----
        hipMemsetAsync(counts, 0, 409600, stream);
        count_kernel<<<E_TH_BLOCKS, 256, 0, stream>>>(edst, counts);
        scan_kernel<<<1, SCAN_T, 0, stream>>>(counts, cursor);
        scatter_kernel<<<E_TH_BLOCKS, 256, 0, stream>>>(esrc, edst, cursor,
                                                        eids_s, src_s, dst_s);
        // ---- conv1 ----
        hipMemsetAsync(aggr, 0, NF, stream);
        edge_sorted_kernel<<<CHUNK_BLOCKS, 256, 0, stream>>>(
            x, ea, src_s, dst_s, eids_s, We1, be1, aggr);
        node_kernel<<<NODE_BLOCKS, 256, 0, stream>>>(x, aggr, eps1, W11, b11, W12, b12, h);
        // ---- conv2 ----
        hipMemsetAsync(aggr, 0, NF, stream);
        edge_sorted_kernel<<<CHUNK_BLOCKS, 256, 0, stream>>>(
            h, ea, src_s, dst_s, eids_s, We2, be2, aggr);
        node_kernel<<<NODE_BLOCKS, 256, 0, stream>>>(h, aggr, eps2, W21, b21, W22, b22, h);
    } else {
        // fallback: verified atomic path
        hipMemsetAsync(aggr, 0, NF, stream);
        edge_kernel<<<2048, 256, 0, stream>>>(x, ea, esrc, edst, We1, be1, aggr);
        node_kernel<<<NODE_BLOCKS, 256, 0, stream>>>(x, aggr, eps1, W11, b11, W12, b12, h);
        hipMemsetAsync(aggr, 0, NF, stream);
        edge_kernel<<<2048, 256, 0, stream>>>(h, ea, esrc, edst, We2, be2, aggr);
        node_kernel<<<NODE_BLOCKS, 256, 0, stream>>>(h, aggr, eps2, W21, b21, W22, b22, h);
    }

    // ---- global_add_pool + head ----
    hipMemsetAsync(pooled, 0, (size_t)N_GRAPHS * 64 * sizeof(float), stream);
    pool_kernel<<<POOL_BLOCKS, 256, 0, stream>>>(h, batch, pooled);
    head_kernel<<<N_GRAPHS, 128, 0, stream>>>(pooled, Wf1, bf1, Wf2, bf2, out);
}

// Round 4
// 990.288 us; speedup vs baseline: 1.4000x; 1.4000x over previous
//
#include <hip/hip_runtime.h>

#define N_NODES 100000
#define N_EDGES 1000000
#define N_GRAPHS 128
#define NPW 8            // dst nodes per wave in edge phase
#define SCAN_BLK 1024
#define SCAN_NB ((N_NODES + SCAN_BLK - 1) / SCAN_BLK)   // 98

// ===========================================================================
// Counting-sort of edges by dst -> CSR. Rebuilt every call (ws re-poisoned).
// ===========================================================================
__global__ __launch_bounds__(256) void count_kernel(
    const int* __restrict__ dst, int* __restrict__ counts)
{
    int e = blockIdx.x * blockDim.x + threadIdx.x;
    if (e < N_EDGES) atomicAdd(&counts[dst[e]], 1);
}

// per-block exclusive scan (Hillis-Steele in LDS), block sums out
__global__ __launch_bounds__(SCAN_BLK) void scan1_kernel(
    const int* __restrict__ counts, int* __restrict__ cursor,
    int* __restrict__ bsum)
{
    __shared__ int sm[SCAN_BLK];
    const int t = threadIdx.x;
    const int i = blockIdx.x * SCAN_BLK + t;
    const int v = (i < N_NODES) ? counts[i] : 0;
    sm[t] = v;
    __syncthreads();
    for (int off = 1; off < SCAN_BLK; off <<= 1) {
        int tmp = (t >= off) ? sm[t - off] : 0;
        __syncthreads();
        sm[t] += tmp;
        __syncthreads();
    }
    if (i < N_NODES) cursor[i] = sm[t] - v;          // exclusive within block
    if (t == SCAN_BLK - 1) bsum[blockIdx.x] = sm[t]; // block total
}

// scan the 98 block sums (one small block)
__global__ __launch_bounds__(128) void scan2_kernel(
    const int* __restrict__ bsum, int* __restrict__ boff)
{
    __shared__ int sm[128];
    const int t = threadIdx.x;
    const int v = (t < SCAN_NB) ? bsum[t] : 0;
    sm[t] = v;
    __syncthreads();
    for (int off = 1; off < 128; off <<= 1) {
        int tmp = (t >= off) ? sm[t - off] : 0;
        __syncthreads();
        sm[t] += tmp;
        __syncthreads();
    }
    if (t < SCAN_NB) boff[t] = sm[t] - v;            // exclusive block offset
}

__global__ __launch_bounds__(SCAN_BLK) void scan3_kernel(
    int* __restrict__ cursor, const int* __restrict__ boff)
{
    const int i = blockIdx.x * SCAN_BLK + threadIdx.x;
    if (i < N_NODES) cursor[i] += boff[blockIdx.x];
}

// scatter edges into dst-sorted order; cursor[n] ends as INCLUSIVE scan,
// i.e. rowend[n] = end offset of node n's edge run.
__global__ __launch_bounds__(256) void scatter_kernel(
    const int* __restrict__ src, const int* __restrict__ dst,
    int* __restrict__ cursor,
    int* __restrict__ eids_s, int* __restrict__ src_s)
{
    int e = blockIdx.x * blockDim.x + threadIdx.x;
    if (e >= N_EDGES) return;
    int d = dst[e];
    int pos = atomicAdd(&cursor[d], 1);
    eids_s[pos] = e;
    src_s[pos]  = src[e];
}

// ===========================================================================
// Edge phase, CSR: one wave per NPW consecutive dst nodes, lane i = feature i.
// Messages accumulate in registers; one PLAIN STORE per node (covers zero-
// degree nodes too -> no aggr memset, no atomics). Weights PINNED in VGPRs.
// ===========================================================================
__global__ __launch_bounds__(256) void edge_csr_kernel(
    const float* __restrict__ x,      // [N,64] conv input
    const float* __restrict__ ea,     // [E,32]
    const int*   __restrict__ src_s,  // [E] src sorted by dst
    const int*   __restrict__ eids_s, // [E] original edge id sorted by dst
    const int*   __restrict__ rowend, // [N] inclusive ends
    const float* __restrict__ We,     // [32,64]
    const float* __restrict__ be,     // [64]
    float*       __restrict__ aggr)   // [N,64]
{
    const int lane = threadIdx.x & 63;
    const int wid  = (blockIdx.x * blockDim.x + threadIdx.x) >> 6;
    const int n0   = __builtin_amdgcn_readfirstlane(wid * NPW);
    if (n0 >= N_NODES) return;
    const int n1 = min(n0 + NPW, N_NODES);

    float w[32];
#pragma unroll
    for (int k = 0; k < 32; ++k) w[k] = We[k * 64 + lane];
    float b = be[lane];
    // pin weights in VGPRs: compiler cannot rematerialize by reloading
#pragma unroll
    for (int k = 0; k < 32; ++k) asm volatile("" : "+v"(w[k]));
    asm volatile("" : "+v"(b));

    int p = (n0 == 0) ? 0 : rowend[n0 - 1];          // uniform s_load
    for (int n = n0; n < n1; ++n) {
        const int pe = rowend[n];                    // uniform s_load
        float acc = 0.0f;
        for (; p < pe; ++p) {
            const int e = eids_s[p];                 // uniform s_load
            const int s = src_s[p];                  // uniform s_load
            const float* er = ea + (size_t)e * 32;   // uniform 128B row
            const float xv = x[(size_t)s * 64 + lane];
            float ev = b;
#pragma unroll
            for (int k = 0; k < 32; ++k)
                ev = fmaf(er[k], w[k], ev);          // sgpr * pinned vgpr
            acc += fmaxf(xv + ev, 0.0f);
        }
        aggr[(size_t)n * 64 + lane] = acc;           // sole writer
    }
}

// ===========================================================================
// Node phase: wave per node batch, lane i owns feature i.
//   out = relu( relu(((1+eps)x+aggr)@W1+b1) @ W2 + b2 )
// Both weight matrices pinned in VGPRs (128 regs).
// ===========================================================================
__global__ __launch_bounds__(256) void node_kernel(
    const float* __restrict__ x_in, const float* __restrict__ aggr,
    const float* __restrict__ eps,
    const float* __restrict__ W1, const float* __restrict__ b1,
    const float* __restrict__ W2, const float* __restrict__ b2,
    float* __restrict__ h_out)
{
    const int lane = threadIdx.x & 63;
    const int wid  = (blockIdx.x * blockDim.x + threadIdx.x) >> 6;
    const int nw   = (gridDim.x * blockDim.x) >> 6;

    float w1[64], w2[64];
#pragma unroll
    for (int i = 0; i < 64; ++i) w1[i] = W1[i * 64 + lane];
#pragma unroll
    for (int i = 0; i < 64; ++i) w2[i] = W2[i * 64 + lane];
#pragma unroll
    for (int i = 0; i < 64; ++i) asm volatile("" : "+v"(w1[i]));
#pragma unroll
    for (int i = 0; i < 64; ++i) asm volatile("" : "+v"(w2[i]));
    const float b1v = b1[lane];
    const float b2v = b2[lane];
    const float ep  = 1.0f + eps[0];

    for (int n = wid; n < N_NODES; n += nw) {
        const size_t base = (size_t)n * 64;
        const float h = fmaf(ep, x_in[base + lane], aggr[base + lane]);

        float t = b1v;
#pragma unroll
        for (int i = 0; i < 64; ++i)
            t = fmaf(__shfl(h, i), w1[i], t);
        t = fmaxf(t, 0.0f);

        float o = b2v;
#pragma unroll
        for (int i = 0; i < 64; ++i)
            o = fmaf(__shfl(t, i), w2[i], o);

        h_out[base + lane] = fmaxf(o, 0.0f);
    }
}

// ===========================================================================
// Pooling (batch sorted): wave per 128-node chunk, atomic per graph-run.
// ===========================================================================
#define POOL_CHUNK 128
__global__ __launch_bounds__(256) void pool_kernel(
    const float* __restrict__ h, const int* __restrict__ batch,
    float* __restrict__ pooled)
{
    const int lane  = threadIdx.x & 63;
    const int wid   = (blockIdx.x * blockDim.x + threadIdx.x) >> 6;
    const int start = wid * POOL_CHUNK;
    if (start >= N_NODES) return;
    const int end = min(start + POOL_CHUNK, N_NODES);

    int   gcur = batch[start];
    float acc  = 0.0f;
    for (int n = start; n < end; ++n) {
        const int g = batch[n];
        if (g != gcur) {
            atomicAdd(&pooled[gcur * 64 + lane], acc);
            acc  = 0.0f;
            gcur = g;
        }
        acc += h[(size_t)n * 64 + lane];
    }
    atomicAdd(&pooled[gcur * 64 + lane], acc);
}

// ===========================================================================
// Head: one block (128 threads) per graph.
// ===========================================================================
__global__ __launch_bounds__(128) void head_kernel(
    const float* __restrict__ pooled, const float* __restrict__ Wf1,
    const float* __restrict__ bf1, const float* __restrict__ Wf2,
    const float* __restrict__ bf2, float* __restrict__ out)
{
    __shared__ float p[64];
    __shared__ float red[2];
    const int g = blockIdx.x;
    const int j = threadIdx.x;

    if (j < 64) p[j] = pooled[g * 64 + j];
    __syncthreads();

    float t = bf1[j];
#pragma unroll
    for (int i = 0; i < 64; ++i)
        t = fmaf(p[i], Wf1[i * 128 + j], t);
    t = fmaxf(t, 0.0f);

    float v = t * Wf2[j];
    for (int off = 32; off > 0; off >>= 1)
        v += __shfl_down(v, off);
    if ((j & 63) == 0) red[j >> 6] = v;
    __syncthreads();
    if (j == 0) out[g] = red[0] + red[1] + bf2[0];
}

extern "C" void kernel_launch(void* const* d_in, const int* in_sizes, int n_in,
                              void* d_out, int out_size, void* d_ws, size_t ws_size,
                              hipStream_t stream) {
    const float* x    = (const float*)d_in[0];
    const float* ea   = (const float*)d_in[1];
    const int*   esrc = (const int*)  d_in[2];
    const int*   edst = (const int*)  d_in[3];
    const int*   batch= (const int*)  d_in[4];
    const float* eps1 = (const float*)d_in[5];
    const float* We1  = (const float*)d_in[6];
    const float* be1  = (const float*)d_in[7];
    const float* W11  = (const float*)d_in[8];
    const float* b11  = (const float*)d_in[9];
    const float* W12  = (const float*)d_in[10];
    const float* b12  = (const float*)d_in[11];
    const float* eps2 = (const float*)d_in[12];
    const float* We2  = (const float*)d_in[13];
    const float* be2  = (const float*)d_in[14];
    const float* W21  = (const float*)d_in[15];
    const float* b21  = (const float*)d_in[16];
    const float* W22  = (const float*)d_in[17];
    const float* b22  = (const float*)d_in[18];
    const float* Wf1  = (const float*)d_in[19];
    const float* bf1  = (const float*)d_in[20];
    const float* Wf2  = (const float*)d_in[21];
    const float* bf2  = (const float*)d_in[22];
    float* out = (float*)d_out;

    // ---- workspace layout (all offsets 256B-aligned) ----
    const size_t NF = (size_t)N_NODES * 64 * sizeof(float);  // 25,600,000
    char* ws = (char*)d_ws;
    float* aggr   = (float*)ws;                        // 25.6 MB
    float* h      = (float*)(ws + NF);                 // 25.6 MB
    float* pooled = (float*)(ws + 2 * NF);             // 32 KB
    char*  p4     = ws + 2 * NF + 32768;
    int* counts = (int*)p4;                            // 409,600 B
    int* cursor = (int*)(p4 + 409600);                 // 409,600 B (-> rowend)
    int* eids_s = (int*)(p4 + 2 * 409600);             // 4,000,000 B
    int* src_s  = (int*)(p4 + 2 * 409600 + 4000000);   // 4,000,000 B
    int* bsum   = (int*)(p4 + 2 * 409600 + 8000000);   // 512 B
    int* boff   = (int*)(p4 + 2 * 409600 + 8000512);   // 512 B

    const int E_TH_BLOCKS = (N_EDGES + 255) / 256;                 // 3907
    const int EDGE_WAVES  = (N_NODES + NPW - 1) / NPW;             // 12500
    const int EDGE_BLOCKS = (EDGE_WAVES + 3) / 4;                  // 3125
    const int NODE_BLOCKS = 1024;
    const int POOL_BLOCKS = ((N_NODES + POOL_CHUNK - 1) / POOL_CHUNK + 3) / 4;

    // ---- build CSR (counts -> scan -> scatter); cursor ends as rowend ----
    hipMemsetAsync(counts, 0, 409600, stream);
    count_kernel<<<E_TH_BLOCKS, 256, 0, stream>>>(edst, counts);
    scan1_kernel<<<SCAN_NB, SCAN_BLK, 0, stream>>>(counts, cursor, bsum);
    scan2_kernel<<<1, 128, 0, stream>>>(bsum, boff);
    scan3_kernel<<<SCAN_NB, SCAN_BLK, 0, stream>>>(cursor, boff);
    scatter_kernel<<<E_TH_BLOCKS, 256, 0, stream>>>(esrc, edst, cursor,
                                                    eids_s, src_s);

    // ---- conv1 ----
    edge_csr_kernel<<<EDGE_BLOCKS, 256, 0, stream>>>(
        x, ea, src_s, eids_s, cursor, We1, be1, aggr);
    node_kernel<<<NODE_BLOCKS, 256, 0, stream>>>(x, aggr, eps1, W11, b11, W12, b12, h);

    // ---- conv2 ----
    edge_csr_kernel<<<EDGE_BLOCKS, 256, 0, stream>>>(
        h, ea, src_s, eids_s, cursor, We2, be2, aggr);
    node_kernel<<<NODE_BLOCKS, 256, 0, stream>>>(h, aggr, eps2, W21, b21, W22, b22, h);

    // ---- global_add_pool + head ----
    hipMemsetAsync(pooled, 0, (size_t)N_GRAPHS * 64 * sizeof(float), stream);
    pool_kernel<<<POOL_BLOCKS, 256, 0, stream>>>(h, batch, pooled);
    head_kernel<<<N_GRAPHS, 128, 0, stream>>>(pooled, Wf1, bf1, Wf2, bf2, out);
}

// Round 5
// 985.881 us; speedup vs baseline: 1.4063x; 1.0045x over previous
//
#include <hip/hip_runtime.h>

#define N_NODES 100000
#define N_EDGES 1000000
#define N_GRAPHS 128
#define NPW 4            // dst nodes per wave in edge phase
#define SCAN_BLK 1024
#define SCAN_NB ((N_NODES + SCAN_BLK - 1) / SCAN_BLK)   // 98

// ===========================================================================
// Counting-sort of edges by dst -> CSR (+ permuted edge attrs).
// ===========================================================================
__global__ __launch_bounds__(256) void count_kernel(
    const int* __restrict__ dst, int* __restrict__ counts)
{
    int e = blockIdx.x * blockDim.x + threadIdx.x;
    if (e < N_EDGES) atomicAdd(&counts[dst[e]], 1);
}

__global__ __launch_bounds__(SCAN_BLK) void scan1_kernel(
    const int* __restrict__ counts, int* __restrict__ cursor,
    int* __restrict__ bsum)
{
    __shared__ int sm[SCAN_BLK];
    const int t = threadIdx.x;
    const int i = blockIdx.x * SCAN_BLK + t;
    const int v = (i < N_NODES) ? counts[i] : 0;
    sm[t] = v;
    __syncthreads();
    for (int off = 1; off < SCAN_BLK; off <<= 1) {
        int tmp = (t >= off) ? sm[t - off] : 0;
        __syncthreads();
        sm[t] += tmp;
        __syncthreads();
    }
    if (i < N_NODES) cursor[i] = sm[t] - v;
    if (t == SCAN_BLK - 1) bsum[blockIdx.x] = sm[t];
}

__global__ __launch_bounds__(128) void scan2_kernel(
    const int* __restrict__ bsum, int* __restrict__ boff)
{
    __shared__ int sm[128];
    const int t = threadIdx.x;
    const int v = (t < SCAN_NB) ? bsum[t] : 0;
    sm[t] = v;
    __syncthreads();
    for (int off = 1; off < 128; off <<= 1) {
        int tmp = (t >= off) ? sm[t - off] : 0;
        __syncthreads();
        sm[t] += tmp;
        __syncthreads();
    }
    if (t < SCAN_NB) boff[t] = sm[t] - v;
}

__global__ __launch_bounds__(SCAN_BLK) void scan3_kernel(
    int* __restrict__ cursor, const int* __restrict__ boff)
{
    const int i = blockIdx.x * SCAN_BLK + threadIdx.x;
    if (i < N_NODES) cursor[i] += boff[blockIdx.x];
}

// Scatter + PHYSICAL PERMUTE of ea: one wave handles 2 edges.
// Lanes 0-31 own edge 2w, lanes 32-63 own edge 2w+1: the ea read is one
// contiguous 256B stretch; the ea_s write is two 128B rows. src_s gets the
// sorted src. cursor[n] ends as INCLUSIVE end (rowend).
__global__ __launch_bounds__(256) void scatter_perm_kernel(
    const int*   __restrict__ src, const int* __restrict__ dst,
    const float* __restrict__ ea,
    int*   __restrict__ cursor,
    int*   __restrict__ src_s,
    float* __restrict__ ea_s)
{
    const int lane = threadIdx.x & 63;
    const int half = lane >> 5;        // 0 or 1
    const int l    = lane & 31;
    const int wid  = (blockIdx.x * blockDim.x + threadIdx.x) >> 6;
    const int e    = wid * 2 + half;
    if (e >= N_EDGES) return;

    int pos;
    if (l == 0) pos = atomicAdd(&cursor[dst[e]], 1);
    pos = __shfl(pos, half << 5);      // broadcast within each half
    if (l == 0) src_s[pos] = src[e];

    const float v = ea[(size_t)e * 32 + l];   // contiguous 256B per wave
    ea_s[(size_t)pos * 32 + l] = v;           // two 128B rows
}

// Fallback scatter (round-4 verified): keeps original-order ea, stores eids.
__global__ __launch_bounds__(256) void scatter_fb_kernel(
    const int* __restrict__ src, const int* __restrict__ dst,
    int* __restrict__ cursor,
    int* __restrict__ eids_s, int* __restrict__ src_s)
{
    int e = blockIdx.x * blockDim.x + threadIdx.x;
    if (e >= N_EDGES) return;
    int d = dst[e];
    int pos = atomicAdd(&cursor[d], 1);
    eids_s[pos] = e;
    src_s[pos]  = src[e];
}

// ===========================================================================
// Edge phase, CSR + permuted ea: one wave per NPW consecutive dst nodes,
// lane i = feature i. ALL edge-side streams (src_s, ea_s, rowend) are
// SEQUENTIAL scalar loads; only the x-row gather is random. One plain store
// per node (zero-degree included -> no memset, no atomics). Weights pinned.
// ===========================================================================
__global__ __launch_bounds__(256) void edge_csr_kernel(
    const float* __restrict__ x,      // [N,64] conv input
    const float* __restrict__ ea_s,   // [E,32] dst-sorted edge attrs
    const int*   __restrict__ src_s,  // [E] src sorted by dst
    const int*   __restrict__ rowend, // [N] inclusive ends
    const float* __restrict__ We,     // [32,64]
    const float* __restrict__ be,     // [64]
    float*       __restrict__ aggr)   // [N,64]
{
    const int lane = threadIdx.x & 63;
    const int wid  = (blockIdx.x * blockDim.x + threadIdx.x) >> 6;
    const int n0   = __builtin_amdgcn_readfirstlane(wid * NPW);
    if (n0 >= N_NODES) return;
    const int n1 = min(n0 + NPW, N_NODES);

    float w[32];
#pragma unroll
    for (int k = 0; k < 32; ++k) w[k] = We[k * 64 + lane];
    float b = be[lane];
#pragma unroll
    for (int k = 0; k < 32; ++k) asm volatile("" : "+v"(w[k]));
    asm volatile("" : "+v"(b));

    int p = (n0 == 0) ? 0 : rowend[n0 - 1];
    for (int n = n0; n < n1; ++n) {
        const int pe = rowend[n];
        float acc = 0.0f;
        for (; p < pe; ++p) {
            const int s = src_s[p];                   // sequential s_load
            const float* er = ea_s + (size_t)p * 32;  // sequential 128B row
            const float xv = x[(size_t)s * 64 + lane];// the one random access
            float e0 = b, e1 = 0.0f, e2 = 0.0f, e3 = 0.0f;
#pragma unroll
            for (int k = 0; k < 32; k += 4) {
                e0 = fmaf(er[k+0], w[k+0], e0);
                e1 = fmaf(er[k+1], w[k+1], e1);
                e2 = fmaf(er[k+2], w[k+2], e2);
                e3 = fmaf(er[k+3], w[k+3], e3);
            }
            acc += fmaxf(xv + ((e0 + e1) + (e2 + e3)), 0.0f);
        }
        aggr[(size_t)n * 64 + lane] = acc;            // sole writer
    }
}

// Fallback edge kernel (round-4 verified): eids indirection into original ea.
__global__ __launch_bounds__(256) void edge_csr_fb_kernel(
    const float* __restrict__ x, const float* __restrict__ ea,
    const int* __restrict__ src_s, const int* __restrict__ eids_s,
    const int* __restrict__ rowend,
    const float* __restrict__ We, const float* __restrict__ be,
    float* __restrict__ aggr)
{
    const int lane = threadIdx.x & 63;
    const int wid  = (blockIdx.x * blockDim.x + threadIdx.x) >> 6;
    const int n0   = __builtin_amdgcn_readfirstlane(wid * NPW);
    if (n0 >= N_NODES) return;
    const int n1 = min(n0 + NPW, N_NODES);

    float w[32];
#pragma unroll
    for (int k = 0; k < 32; ++k) w[k] = We[k * 64 + lane];
    float b = be[lane];
#pragma unroll
    for (int k = 0; k < 32; ++k) asm volatile("" : "+v"(w[k]));
    asm volatile("" : "+v"(b));

    int p = (n0 == 0) ? 0 : rowend[n0 - 1];
    for (int n = n0; n < n1; ++n) {
        const int pe = rowend[n];
        float acc = 0.0f;
        for (; p < pe; ++p) {
            const int e = eids_s[p];
            const int s = src_s[p];
            const float* er = ea + (size_t)e * 32;
            const float xv = x[(size_t)s * 64 + lane];
            float ev = b;
#pragma unroll
            for (int k = 0; k < 32; ++k)
                ev = fmaf(er[k], w[k], ev);
            acc += fmaxf(xv + ev, 0.0f);
        }
        aggr[(size_t)n * 64 + lane] = acc;
    }
}

// ===========================================================================
// Node phase: wave per node, lane i owns feature i.
//   out = relu( relu(((1+eps)x+aggr)@W1+b1) @ W2 + b2 )
// ===========================================================================
__global__ __launch_bounds__(256) void node_kernel(
    const float* __restrict__ x_in, const float* __restrict__ aggr,
    const float* __restrict__ eps,
    const float* __restrict__ W1, const float* __restrict__ b1,
    const float* __restrict__ W2, const float* __restrict__ b2,
    float* __restrict__ h_out)
{
    const int lane = threadIdx.x & 63;
    const int wid  = (blockIdx.x * blockDim.x + threadIdx.x) >> 6;
    const int nw   = (gridDim.x * blockDim.x) >> 6;

    float w1[64], w2[64];
#pragma unroll
    for (int i = 0; i < 64; ++i) w1[i] = W1[i * 64 + lane];
#pragma unroll
    for (int i = 0; i < 64; ++i) w2[i] = W2[i * 64 + lane];
#pragma unroll
    for (int i = 0; i < 64; ++i) asm volatile("" : "+v"(w1[i]));
#pragma unroll
    for (int i = 0; i < 64; ++i) asm volatile("" : "+v"(w2[i]));
    const float b1v = b1[lane];
    const float b2v = b2[lane];
    const float ep  = 1.0f + eps[0];

    for (int n = wid; n < N_NODES; n += nw) {
        const size_t base = (size_t)n * 64;
        const float h = fmaf(ep, x_in[base + lane], aggr[base + lane]);

        float t = b1v;
#pragma unroll
        for (int i = 0; i < 64; ++i)
            t = fmaf(__shfl(h, i), w1[i], t);
        t = fmaxf(t, 0.0f);

        float o = b2v;
#pragma unroll
        for (int i = 0; i < 64; ++i)
            o = fmaf(__shfl(t, i), w2[i], o);

        h_out[base + lane] = fmaxf(o, 0.0f);
    }
}

// ===========================================================================
// Pooling (batch sorted): wave per 16-node chunk (6250 waves), atomic per
// graph-run within chunk.
// ===========================================================================
#define POOL_CHUNK 16
__global__ __launch_bounds__(256) void pool_kernel(
    const float* __restrict__ h, const int* __restrict__ batch,
    float* __restrict__ pooled)
{
    const int lane  = threadIdx.x & 63;
    const int wid   = (blockIdx.x * blockDim.x + threadIdx.x) >> 6;
    const int start = wid * POOL_CHUNK;
    if (start >= N_NODES) return;
    const int end = min(start + POOL_CHUNK, N_NODES);

    int   gcur = batch[start];
    float acc  = 0.0f;
    for (int n = start; n < end; ++n) {
        const int g = batch[n];
        if (g != gcur) {
            atomicAdd(&pooled[gcur * 64 + lane], acc);
            acc  = 0.0f;
            gcur = g;
        }
        acc += h[(size_t)n * 64 + lane];
    }
    atomicAdd(&pooled[gcur * 64 + lane], acc);
}

// ===========================================================================
// Head: one block (128 threads) per graph.
// ===========================================================================
__global__ __launch_bounds__(128) void head_kernel(
    const float* __restrict__ pooled, const float* __restrict__ Wf1,
    const float* __restrict__ bf1, const float* __restrict__ Wf2,
    const float* __restrict__ bf2, float* __restrict__ out)
{
    __shared__ float p[64];
    __shared__ float red[2];
    const int g = blockIdx.x;
    const int j = threadIdx.x;

    if (j < 64) p[j] = pooled[g * 64 + j];
    __syncthreads();

    float t = bf1[j];
#pragma unroll
    for (int i = 0; i < 64; ++i)
        t = fmaf(p[i], Wf1[i * 128 + j], t);
    t = fmaxf(t, 0.0f);

    float v = t * Wf2[j];
    for (int off = 32; off > 0; off >>= 1)
        v += __shfl_down(v, off);
    if ((j & 63) == 0) red[j >> 6] = v;
    __syncthreads();
    if (j == 0) out[g] = red[0] + red[1] + bf2[0];
}

extern "C" void kernel_launch(void* const* d_in, const int* in_sizes, int n_in,
                              void* d_out, int out_size, void* d_ws, size_t ws_size,
                              hipStream_t stream) {
    const float* x    = (const float*)d_in[0];
    const float* ea   = (const float*)d_in[1];
    const int*   esrc = (const int*)  d_in[2];
    const int*   edst = (const int*)  d_in[3];
    const int*   batch= (const int*)  d_in[4];
    const float* eps1 = (const float*)d_in[5];
    const float* We1  = (const float*)d_in[6];
    const float* be1  = (const float*)d_in[7];
    const float* W11  = (const float*)d_in[8];
    const float* b11  = (const float*)d_in[9];
    const float* W12  = (const float*)d_in[10];
    const float* b12  = (const float*)d_in[11];
    const float* eps2 = (const float*)d_in[12];
    const float* We2  = (const float*)d_in[13];
    const float* be2  = (const float*)d_in[14];
    const float* W21  = (const float*)d_in[15];
    const float* b21  = (const float*)d_in[16];
    const float* W22  = (const float*)d_in[17];
    const float* b22  = (const float*)d_in[18];
    const float* Wf1  = (const float*)d_in[19];
    const float* bf1  = (const float*)d_in[20];
    const float* Wf2  = (const float*)d_in[21];
    const float* bf2  = (const float*)d_in[22];
    float* out = (float*)d_out;

    // ---- workspace layout ----
    const size_t NF = (size_t)N_NODES * 64 * sizeof(float);  // 25,600,000
    char* ws = (char*)d_ws;
    float* aggr   = (float*)ws;                        // 25.6 MB
    float* h      = (float*)(ws + NF);                 // 25.6 MB
    float* pooled = (float*)(ws + 2 * NF);             // 32 KB
    char*  p4     = ws + 2 * NF + 32768;
    int* counts = (int*)p4;                            // 409,600 B
    int* cursor = (int*)(p4 + 409600);                 // 409,600 B (-> rowend)
    int* src_s  = (int*)(p4 + 2 * 409600);             // 4,000,000 B
    int* bsum   = (int*)(p4 + 2 * 409600 + 4000000);   // 512 B
    int* boff   = (int*)(p4 + 2 * 409600 + 4000512);   // 512 B
    char*  p5   = p4 + 2 * 409600 + 4001024;
    float* ea_s = (float*)p5;                          // 128,000,000 B
    int*   eids_s = (int*)p5;                          // (fallback) 4,000,000 B
    const size_t need_fast = (size_t)(p5 - ws) + 128000000;
    const size_t need_fb   = (size_t)(p5 - ws) + 4000000;

    const int E_TH_BLOCKS  = (N_EDGES + 255) / 256;                 // 3907
    const int PERM_BLOCKS  = (N_EDGES / 2 + 3) / 4;                 // 125000
    const int EDGE_WAVES   = (N_NODES + NPW - 1) / NPW;             // 25000
    const int EDGE_BLOCKS  = (EDGE_WAVES + 3) / 4;                  // 6250
    const int NODE_BLOCKS  = 1024;
    const int POOL_BLOCKS  = ((N_NODES + POOL_CHUNK - 1) / POOL_CHUNK + 3) / 4;

    // ---- CSR build: counts -> 3-stage scan -> scatter(+permute) ----
    hipMemsetAsync(counts, 0, 409600, stream);
    count_kernel<<<E_TH_BLOCKS, 256, 0, stream>>>(edst, counts);
    scan1_kernel<<<SCAN_NB, SCAN_BLK, 0, stream>>>(counts, cursor, bsum);
    scan2_kernel<<<1, 128, 0, stream>>>(bsum, boff);
    scan3_kernel<<<SCAN_NB, SCAN_BLK, 0, stream>>>(cursor, boff);

    if (ws_size >= need_fast) {
        scatter_perm_kernel<<<PERM_BLOCKS, 256, 0, stream>>>(
            esrc, edst, ea, cursor, src_s, ea_s);
        // conv1
        edge_csr_kernel<<<EDGE_BLOCKS, 256, 0, stream>>>(
            x, ea_s, src_s, cursor, We1, be1, aggr);
        node_kernel<<<NODE_BLOCKS, 256, 0, stream>>>(x, aggr, eps1, W11, b11, W12, b12, h);
        // conv2
        edge_csr_kernel<<<EDGE_BLOCKS, 256, 0, stream>>>(
            h, ea_s, src_s, cursor, We2, be2, aggr);
        node_kernel<<<NODE_BLOCKS, 256, 0, stream>>>(h, aggr, eps2, W21, b21, W22, b22, h);
    } else {
        scatter_fb_kernel<<<E_TH_BLOCKS, 256, 0, stream>>>(
            esrc, edst, cursor, eids_s, src_s);
        edge_csr_fb_kernel<<<EDGE_BLOCKS, 256, 0, stream>>>(
            x, ea, src_s, eids_s, cursor, We1, be1, aggr);
        node_kernel<<<NODE_BLOCKS, 256, 0, stream>>>(x, aggr, eps1, W11, b11, W12, b12, h);
        edge_csr_fb_kernel<<<EDGE_BLOCKS, 256, 0, stream>>>(
            h, ea, src_s, eids_s, cursor, We2, be2, aggr);
        node_kernel<<<NODE_BLOCKS, 256, 0, stream>>>(h, aggr, eps2, W21, b21, W22, b22, h);
    }

    // ---- global_add_pool + head ----
    hipMemsetAsync(pooled, 0, (size_t)N_GRAPHS * 64 * sizeof(float), stream);
    pool_kernel<<<POOL_BLOCKS, 256, 0, stream>>>(h, batch, pooled);
    head_kernel<<<N_GRAPHS, 128, 0, stream>>>(pooled, Wf1, bf1, Wf2, bf2, out);
}

// Round 7
// 848.424 us; speedup vs baseline: 1.6341x; 1.1620x over previous
//
#include <hip/hip_runtime.h>

#define N_NODES 100000
#define N_EDGES 1000000
#define N_GRAPHS 128
#define NPW 4            // dst nodes per wave in edge phase
#define SCAN_BLK 1024
#define SCAN_NB ((N_NODES + SCAN_BLK - 1) / SCAN_BLK)   // 98

// ===========================================================================
// Counting-sort of edges by dst -> CSR (+ permuted edge attrs).
// ===========================================================================
__global__ __launch_bounds__(256) void count_kernel(
    const int* __restrict__ dst, int* __restrict__ counts)
{
    int e = blockIdx.x * blockDim.x + threadIdx.x;
    if (e < N_EDGES) atomicAdd(&counts[dst[e]], 1);
}

__global__ __launch_bounds__(SCAN_BLK) void scan1_kernel(
    const int* __restrict__ counts, int* __restrict__ cursor,
    int* __restrict__ bsum)
{
    __shared__ int sm[SCAN_BLK];
    const int t = threadIdx.x;
    const int i = blockIdx.x * SCAN_BLK + t;
    const int v = (i < N_NODES) ? counts[i] : 0;
    sm[t] = v;
    __syncthreads();
    for (int off = 1; off < SCAN_BLK; off <<= 1) {
        int tmp = (t >= off) ? sm[t - off] : 0;
        __syncthreads();
        sm[t] += tmp;
        __syncthreads();
    }
    if (i < N_NODES) cursor[i] = sm[t] - v;
    if (t == SCAN_BLK - 1) bsum[blockIdx.x] = sm[t];
}

__global__ __launch_bounds__(128) void scan2_kernel(
    const int* __restrict__ bsum, int* __restrict__ boff)
{
    __shared__ int sm[128];
    const int t = threadIdx.x;
    const int v = (t < SCAN_NB) ? bsum[t] : 0;
    sm[t] = v;
    __syncthreads();
    for (int off = 1; off < 128; off <<= 1) {
        int tmp = (t >= off) ? sm[t - off] : 0;
        __syncthreads();
        sm[t] += tmp;
        __syncthreads();
    }
    if (t < SCAN_NB) boff[t] = sm[t] - v;
}

__global__ __launch_bounds__(SCAN_BLK) void scan3_kernel(
    int* __restrict__ cursor, const int* __restrict__ boff)
{
    const int i = blockIdx.x * SCAN_BLK + threadIdx.x;
    if (i < N_NODES) cursor[i] += boff[blockIdx.x];
}

// ---------------------------------------------------------------------------
// Scatter + permute, 8 edges per wave. Lane r<8 does the atomic for edge
// ebase+r and writes src_s; all 64 lanes move edge-attr data as float4:
// row r = lanes 8r..8r+7, lane covers 16B. Read = one coalesced 1KB stretch;
// write = 8 independent random 128B rows in one dwordx4 store instruction.
// cursor[n] ends as INCLUSIVE end (rowend). N_EDGES divisible by 8.
// ---------------------------------------------------------------------------
__global__ __launch_bounds__(256) void scatter_perm_kernel(
    const int*   __restrict__ src, const int* __restrict__ dst,
    const float* __restrict__ ea,
    int*   __restrict__ cursor,
    int*   __restrict__ src_s,
    float* __restrict__ ea_s)
{
    const int lane  = threadIdx.x & 63;
    const int wid   = (blockIdx.x * blockDim.x + threadIdx.x) >> 6;
    const int r     = lane >> 3;      // row within wave, 0..7
    const int q     = lane & 7;       // 16B chunk within row, 0..7
    const int ebase = wid * 8;
    if (ebase >= N_EDGES) return;

    int pos = 0;
    if (lane < 8) {
        const int e = ebase + lane;
        pos = atomicAdd(&cursor[dst[e]], 1);
        src_s[pos] = src[e];
    }
    const int mypos = __shfl(pos, r);   // broadcast row r's position

    const float4 v = *(const float4*)(ea + (size_t)(ebase + r) * 32 + q * 4);
    *(float4*)(ea_s + (size_t)mypos * 32 + q * 4) = v;
}

// Fallback scatter (verified): keeps original-order ea, stores eids.
__global__ __launch_bounds__(256) void scatter_fb_kernel(
    const int* __restrict__ src, const int* __restrict__ dst,
    int* __restrict__ cursor,
    int* __restrict__ eids_s, int* __restrict__ src_s)
{
    int e = blockIdx.x * blockDim.x + threadIdx.x;
    if (e >= N_EDGES) return;
    int d = dst[e];
    int pos = atomicAdd(&cursor[d], 1);
    eids_s[pos] = e;
    src_s[pos]  = src[e];
}

// ===========================================================================
// Edge phase, CSR + permuted ea: one wave per NPW consecutive dst nodes,
// lane i = feature i. Inner loop processes TWO edges per iteration with
// 8 independent FMA chains (4 per edge) + 2 independent x-gathers -> the
// sequential row loads pipeline under the FMAs. One plain store per node.
// ===========================================================================
__global__ __launch_bounds__(256) void edge_csr_kernel(
    const float* __restrict__ x,      // [N,64] conv input
    const float* __restrict__ ea_s,   // [E,32] dst-sorted edge attrs
    const int*   __restrict__ src_s,  // [E] src sorted by dst
    const int*   __restrict__ rowend, // [N] inclusive ends
    const float* __restrict__ We,     // [32,64]
    const float* __restrict__ be,     // [64]
    float*       __restrict__ aggr)   // [N,64]
{
    const int lane = threadIdx.x & 63;
    const int wid  = (blockIdx.x * blockDim.x + threadIdx.x) >> 6;
    const int n0   = __builtin_amdgcn_readfirstlane(wid * NPW);
    if (n0 >= N_NODES) return;
    const int n1 = min(n0 + NPW, N_NODES);

    float w[32];
#pragma unroll
    for (int k = 0; k < 32; ++k) w[k] = We[k * 64 + lane];
    float b = be[lane];
#pragma unroll
    for (int k = 0; k < 32; ++k) asm volatile("" : "+v"(w[k]));
    asm volatile("" : "+v"(b));

    int p = (n0 == 0) ? 0 : rowend[n0 - 1];
    for (int n = n0; n < n1; ++n) {
        const int pe = rowend[n];
        float acc = 0.0f;
        // ---- 2-edge pipelined body ----
        for (; p + 2 <= pe; p += 2) {
            const float* er0 = ea_s + (size_t)p * 32;   // sequential rows
            const float* er1 = er0 + 32;
            const int s0 = src_s[p];
            const int s1 = src_s[p + 1];
            const float xv0 = x[(size_t)s0 * 64 + lane];
            const float xv1 = x[(size_t)s1 * 64 + lane];
            float a0 = b, a1 = 0.f, a2 = 0.f, a3 = 0.f;
            float c0 = b, c1 = 0.f, c2 = 0.f, c3 = 0.f;
#pragma unroll
            for (int k = 0; k < 32; k += 4) {
                a0 = fmaf(er0[k+0], w[k+0], a0);
                a1 = fmaf(er0[k+1], w[k+1], a1);
                a2 = fmaf(er0[k+2], w[k+2], a2);
                a3 = fmaf(er0[k+3], w[k+3], a3);
                c0 = fmaf(er1[k+0], w[k+0], c0);
                c1 = fmaf(er1[k+1], w[k+1], c1);
                c2 = fmaf(er1[k+2], w[k+2], c2);
                c3 = fmaf(er1[k+3], w[k+3], c3);
            }
            acc += fmaxf(xv0 + ((a0 + a1) + (a2 + a3)), 0.0f)
                 + fmaxf(xv1 + ((c0 + c1) + (c2 + c3)), 0.0f);
        }
        // ---- odd tail edge ----
        if (p < pe) {
            const float* er = ea_s + (size_t)p * 32;
            const int s = src_s[p];
            const float xv = x[(size_t)s * 64 + lane];
            float a0 = b, a1 = 0.f, a2 = 0.f, a3 = 0.f;
#pragma unroll
            for (int k = 0; k < 32; k += 4) {
                a0 = fmaf(er[k+0], w[k+0], a0);
                a1 = fmaf(er[k+1], w[k+1], a1);
                a2 = fmaf(er[k+2], w[k+2], a2);
                a3 = fmaf(er[k+3], w[k+3], a3);
            }
            acc += fmaxf(xv + ((a0 + a1) + (a2 + a3)), 0.0f);
            ++p;
        }
        aggr[(size_t)n * 64 + lane] = acc;   // sole writer
    }
}

// Fallback edge kernel (verified): eids indirection into original ea.
__global__ __launch_bounds__(256) void edge_csr_fb_kernel(
    const float* __restrict__ x, const float* __restrict__ ea,
    const int* __restrict__ src_s, const int* __restrict__ eids_s,
    const int* __restrict__ rowend,
    const float* __restrict__ We, const float* __restrict__ be,
    float* __restrict__ aggr)
{
    const int lane = threadIdx.x & 63;
    const int wid  = (blockIdx.x * blockDim.x + threadIdx.x) >> 6;
    const int n0   = __builtin_amdgcn_readfirstlane(wid * NPW);
    if (n0 >= N_NODES) return;
    const int n1 = min(n0 + NPW, N_NODES);

    float w[32];
#pragma unroll
    for (int k = 0; k < 32; ++k) w[k] = We[k * 64 + lane];
    float b = be[lane];
#pragma unroll
    for (int k = 0; k < 32; ++k) asm volatile("" : "+v"(w[k]));
    asm volatile("" : "+v"(b));

    int p = (n0 == 0) ? 0 : rowend[n0 - 1];
    for (int n = n0; n < n1; ++n) {
        const int pe = rowend[n];
        float acc = 0.0f;
        for (; p < pe; ++p) {
            const int e = eids_s[p];
            const int s = src_s[p];
            const float* er = ea + (size_t)e * 32;
            const float xv = x[(size_t)s * 64 + lane];
            float ev = b;
#pragma unroll
            for (int k = 0; k < 32; ++k)
                ev = fmaf(er[k], w[k], ev);
            acc += fmaxf(xv + ev, 0.0f);
        }
        aggr[(size_t)n * 64 + lane] = acc;
    }
}

// ===========================================================================
// Node phase: wave per node, lane i owns feature i. Each 64-FMA dot product
// split into 4 independent chains (latency 4cy x 16 deep instead of x 64).
//   out = relu( relu(((1+eps)x+aggr)@W1+b1) @ W2 + b2 )
// ===========================================================================
__global__ __launch_bounds__(256) void node_kernel(
    const float* __restrict__ x_in, const float* __restrict__ aggr,
    const float* __restrict__ eps,
    const float* __restrict__ W1, const float* __restrict__ b1,
    const float* __restrict__ W2, const float* __restrict__ b2,
    float* __restrict__ h_out)
{
    const int lane = threadIdx.x & 63;
    const int wid  = (blockIdx.x * blockDim.x + threadIdx.x) >> 6;
    const int nw   = (gridDim.x * blockDim.x) >> 6;

    float w1[64], w2[64];
#pragma unroll
    for (int i = 0; i < 64; ++i) w1[i] = W1[i * 64 + lane];
#pragma unroll
    for (int i = 0; i < 64; ++i) w2[i] = W2[i * 64 + lane];
#pragma unroll
    for (int i = 0; i < 64; ++i) asm volatile("" : "+v"(w1[i]));
#pragma unroll
    for (int i = 0; i < 64; ++i) asm volatile("" : "+v"(w2[i]));
    const float b1v = b1[lane];
    const float b2v = b2[lane];
    const float ep  = 1.0f + eps[0];

    for (int n = wid; n < N_NODES; n += nw) {
        const size_t base = (size_t)n * 64;
        const float h = fmaf(ep, x_in[base + lane], aggr[base + lane]);

        float t0 = b1v, t1 = 0.f, t2 = 0.f, t3 = 0.f;
#pragma unroll
        for (int i = 0; i < 64; i += 4) {
            t0 = fmaf(__shfl(h, i+0), w1[i+0], t0);
            t1 = fmaf(__shfl(h, i+1), w1[i+1], t1);
            t2 = fmaf(__shfl(h, i+2), w1[i+2], t2);
            t3 = fmaf(__shfl(h, i+3), w1[i+3], t3);
        }
        const float t = fmaxf((t0 + t1) + (t2 + t3), 0.0f);

        float o0 = b2v, o1 = 0.f, o2 = 0.f, o3 = 0.f;
#pragma unroll
        for (int i = 0; i < 64; i += 4) {
            o0 = fmaf(__shfl(t, i+0), w2[i+0], o0);
            o1 = fmaf(__shfl(t, i+1), w2[i+1], o1);
            o2 = fmaf(__shfl(t, i+2), w2[i+2], o2);
            o3 = fmaf(__shfl(t, i+3), w2[i+3], o3);
        }
        h_out[base + lane] = fmaxf((o0 + o1) + (o2 + o3), 0.0f);
    }
}

// ===========================================================================
// Pooling (batch sorted): wave per 16-node chunk, atomic per graph-run.
// ===========================================================================
#define POOL_CHUNK 16
__global__ __launch_bounds__(256) void pool_kernel(
    const float* __restrict__ h, const int* __restrict__ batch,
    float* __restrict__ pooled)
{
    const int lane  = threadIdx.x & 63;
    const int wid   = (blockIdx.x * blockDim.x + threadIdx.x) >> 6;
    const int start = wid * POOL_CHUNK;
    if (start >= N_NODES) return;
    const int end = min(start + POOL_CHUNK, N_NODES);

    int   gcur = batch[start];
    float acc  = 0.0f;
    for (int n = start; n < end; ++n) {
        const int g = batch[n];
        if (g != gcur) {
            atomicAdd(&pooled[gcur * 64 + lane], acc);
            acc  = 0.0f;
            gcur = g;
        }
        acc += h[(size_t)n * 64 + lane];
    }
    atomicAdd(&pooled[gcur * 64 + lane], acc);
}

// ===========================================================================
// Head: one block (128 threads) per graph.
// ===========================================================================
__global__ __launch_bounds__(128) void head_kernel(
    const float* __restrict__ pooled, const float* __restrict__ Wf1,
    const float* __restrict__ bf1, const float* __restrict__ Wf2,
    const float* __restrict__ bf2, float* __restrict__ out)
{
    __shared__ float p[64];
    __shared__ float red[2];
    const int g = blockIdx.x;
    const int j = threadIdx.x;

    if (j < 64) p[j] = pooled[g * 64 + j];
    __syncthreads();

    float t = bf1[j];
#pragma unroll
    for (int i = 0; i < 64; ++i)
        t = fmaf(p[i], Wf1[i * 128 + j], t);
    t = fmaxf(t, 0.0f);

    float v = t * Wf2[j];
    for (int off = 32; off > 0; off >>= 1)
        v += __shfl_down(v, off);
    if ((j & 63) == 0) red[j >> 6] = v;
    __syncthreads();
    if (j == 0) out[g] = red[0] + red[1] + bf2[0];
}

extern "C" void kernel_launch(void* const* d_in, const int* in_sizes, int n_in,
                              void* d_out, int out_size, void* d_ws, size_t ws_size,
                              hipStream_t stream) {
    const float* x    = (const float*)d_in[0];
    const float* ea   = (const float*)d_in[1];
    const int*   esrc = (const int*)  d_in[2];
    const int*   edst = (const int*)  d_in[3];
    const int*   batch= (const int*)  d_in[4];
    const float* eps1 = (const float*)d_in[5];
    const float* We1  = (const float*)d_in[6];
    const float* be1  = (const float*)d_in[7];
    const float* W11  = (const float*)d_in[8];
    const float* b11  = (const float*)d_in[9];
    const float* W12  = (const float*)d_in[10];
    const float* b12  = (const float*)d_in[11];
    const float* eps2 = (const float*)d_in[12];
    const float* We2  = (const float*)d_in[13];
    const float* be2  = (const float*)d_in[14];
    const float* W21  = (const float*)d_in[15];
    const float* b21  = (const float*)d_in[16];
    const float* W22  = (const float*)d_in[17];
    const float* b22  = (const float*)d_in[18];
    const float* Wf1  = (const float*)d_in[19];
    const float* bf1  = (const float*)d_in[20];
    const float* Wf2  = (const float*)d_in[21];
    const float* bf2  = (const float*)d_in[22];
    float* out = (float*)d_out;

    // ---- workspace layout ----
    const size_t NF = (size_t)N_NODES * 64 * sizeof(float);  // 25,600,000
    char* ws = (char*)d_ws;
    float* aggr   = (float*)ws;                        // 25.6 MB
    float* h      = (float*)(ws + NF);                 // 25.6 MB
    float* pooled = (float*)(ws + 2 * NF);             // 32 KB
    char*  p4     = ws + 2 * NF + 32768;
    int* counts = (int*)p4;                            // 409,600 B
    int* cursor = (int*)(p4 + 409600);                 // 409,600 B (-> rowend)
    int* src_s  = (int*)(p4 + 2 * 409600);             // 4,000,000 B
    int* bsum   = (int*)(p4 + 2 * 409600 + 4000000);   // 512 B
    int* boff   = (int*)(p4 + 2 * 409600 + 4000512);   // 512 B
    char*  p5   = p4 + 2 * 409600 + 4001024;
    float* ea_s = (float*)p5;                          // 128,000,000 B
    int*   eids_s = (int*)p5;                          // (fallback) 4,000,000 B
    const size_t need_fast = (size_t)(p5 - ws) + 128000000;

    const int E_TH_BLOCKS  = (N_EDGES + 255) / 256;                 // 3907
    const int PERM_BLOCKS  = (N_EDGES / 8 + 3) / 4;                 // 31250
    const int EDGE_WAVES   = (N_NODES + NPW - 1) / NPW;             // 25000
    const int EDGE_BLOCKS  = (EDGE_WAVES + 3) / 4;                  // 6250
    const int NODE_BLOCKS  = 1024;
    const int POOL_BLOCKS  = ((N_NODES + POOL_CHUNK - 1) / POOL_CHUNK + 3) / 4;

    // ---- CSR build: counts -> 3-stage scan -> scatter(+permute) ----
    hipMemsetAsync(counts, 0, 409600, stream);
    count_kernel<<<E_TH_BLOCKS, 256, 0, stream>>>(edst, counts);
    scan1_kernel<<<SCAN_NB, SCAN_BLK, 0, stream>>>(counts, cursor, bsum);
    scan2_kernel<<<1, 128, 0, stream>>>(bsum, boff);
    scan3_kernel<<<SCAN_NB, SCAN_BLK, 0, stream>>>(cursor, boff);

    if (ws_size >= need_fast) {
        scatter_perm_kernel<<<PERM_BLOCKS, 256, 0, stream>>>(
            esrc, edst, ea, cursor, src_s, ea_s);
        // conv1
        edge_csr_kernel<<<EDGE_BLOCKS, 256, 0, stream>>>(
            x, ea_s, src_s, cursor, We1, be1, aggr);
        node_kernel<<<NODE_BLOCKS, 256, 0, stream>>>(x, aggr, eps1, W11, b11, W12, b12, h);
        // conv2
        edge_csr_kernel<<<EDGE_BLOCKS, 256, 0, stream>>>(
            h, ea_s, src_s, cursor, We2, be2, aggr);
        node_kernel<<<NODE_BLOCKS, 256, 0, stream>>>(h, aggr, eps2, W21, b21, W22, b22, h);
    } else {
        scatter_fb_kernel<<<E_TH_BLOCKS, 256, 0, stream>>>(
            esrc, edst, cursor, eids_s, src_s);
        edge_csr_fb_kernel<<<EDGE_BLOCKS, 256, 0, stream>>>(
            x, ea, src_s, eids_s, cursor, We1, be1, aggr);
        node_kernel<<<NODE_BLOCKS, 256, 0, stream>>>(x, aggr, eps1, W11, b11, W12, b12, h);
        edge_csr_fb_kernel<<<EDGE_BLOCKS, 256, 0, stream>>>(
            h, ea, src_s, eids_s, cursor, We2, be2, aggr);
        node_kernel<<<NODE_BLOCKS, 256, 0, stream>>>(h, aggr, eps2, W21, b21, W22, b22, h);
    }

    // ---- global_add_pool + head ----
    hipMemsetAsync(pooled, 0, (size_t)N_GRAPHS * 64 * sizeof(float), stream);
    pool_kernel<<<POOL_BLOCKS, 256, 0, stream>>>(h, batch, pooled);
    head_kernel<<<N_GRAPHS, 128, 0, stream>>>(pooled, Wf1, bf1, Wf2, bf2, out);
}

// Round 8
// 710.797 us; speedup vs baseline: 1.9505x; 1.1936x over previous
//
#include <hip/hip_runtime.h>

#define N_NODES 100000
#define N_EDGES 1000000
#define N_GRAPHS 128
#define NPW 4            // dst nodes per wave in edge phase
#define SCAN_BLK 1024
#define SCAN_NB ((N_NODES + SCAN_BLK - 1) / SCAN_BLK)   // 98

// guaranteed v_readlane broadcast (NOT __shfl, which may lower to ds_bpermute)
__device__ __forceinline__ float rl(float v, int l) {
    return __uint_as_float(__builtin_amdgcn_readlane(__float_as_uint(v), l));
}

// ===========================================================================
// Counting-sort of edges by dst -> CSR (+ permuted edge attrs).
// ===========================================================================
__global__ __launch_bounds__(256) void count_kernel(
    const int* __restrict__ dst, int* __restrict__ counts)
{
    int e = blockIdx.x * blockDim.x + threadIdx.x;
    if (e < N_EDGES) atomicAdd(&counts[dst[e]], 1);
}

__global__ __launch_bounds__(SCAN_BLK) void scan1_kernel(
    const int* __restrict__ counts, int* __restrict__ cursor,
    int* __restrict__ bsum)
{
    __shared__ int sm[SCAN_BLK];
    const int t = threadIdx.x;
    const int i = blockIdx.x * SCAN_BLK + t;
    const int v = (i < N_NODES) ? counts[i] : 0;
    sm[t] = v;
    __syncthreads();
    for (int off = 1; off < SCAN_BLK; off <<= 1) {
        int tmp = (t >= off) ? sm[t - off] : 0;
        __syncthreads();
        sm[t] += tmp;
        __syncthreads();
    }
    if (i < N_NODES) cursor[i] = sm[t] - v;
    if (t == SCAN_BLK - 1) bsum[blockIdx.x] = sm[t];
}

__global__ __launch_bounds__(128) void scan2_kernel(
    const int* __restrict__ bsum, int* __restrict__ boff)
{
    __shared__ int sm[128];
    const int t = threadIdx.x;
    const int v = (t < SCAN_NB) ? bsum[t] : 0;
    sm[t] = v;
    __syncthreads();
    for (int off = 1; off < 128; off <<= 1) {
        int tmp = (t >= off) ? sm[t - off] : 0;
        __syncthreads();
        sm[t] += tmp;
        __syncthreads();
    }
    if (t < SCAN_NB) boff[t] = sm[t] - v;
}

__global__ __launch_bounds__(SCAN_BLK) void scan3_kernel(
    int* __restrict__ cursor, const int* __restrict__ boff)
{
    const int i = blockIdx.x * SCAN_BLK + threadIdx.x;
    if (i < N_NODES) cursor[i] += boff[blockIdx.x];
}

// ---------------------------------------------------------------------------
// Scatter pass 1: position assignment only (atomic); pos_s[e] = slot.
// cursor[n] ends as INCLUSIVE end (rowend). src_s written here (4B scatter).
// ---------------------------------------------------------------------------
__global__ __launch_bounds__(256) void pos_kernel(
    const int* __restrict__ src, const int* __restrict__ dst,
    int* __restrict__ cursor,
    int* __restrict__ pos_s, int* __restrict__ src_s)
{
    int e = blockIdx.x * blockDim.x + threadIdx.x;
    if (e >= N_EDGES) return;
    int p = atomicAdd(&cursor[dst[e]], 1);
    pos_s[e] = p;
    src_s[p] = src[e];
}

// ---------------------------------------------------------------------------
// Scatter pass 2: pure data move, 8 edges per wave. No atomic dependency:
// store address comes from a sequential pos_s load -> fully pipelined.
// Read = coalesced 1KB; write = 8 random 128B rows per dwordx4 instruction.
// ---------------------------------------------------------------------------
__global__ __launch_bounds__(256) void perm_kernel(
    const float* __restrict__ ea, const int* __restrict__ pos_s,
    float* __restrict__ ea_s)
{
    const int lane  = threadIdx.x & 63;
    const int wid   = (blockIdx.x * blockDim.x + threadIdx.x) >> 6;
    const int r     = lane >> 3;      // row within wave, 0..7
    const int q     = lane & 7;       // 16B chunk within row, 0..7
    const int ebase = wid * 8;
    if (ebase >= N_EDGES) return;

    const int mypos = pos_s[ebase + r];   // 8 lanes share each value
    const float4 v = *(const float4*)(ea + (size_t)(ebase + r) * 32 + q * 4);
    *(float4*)(ea_s + (size_t)mypos * 32 + q * 4) = v;
}

// ===========================================================================
// Edge phase, CSR + permuted ea: one wave per NPW consecutive dst nodes,
// lane i = feature i. The 2 edge-attr rows per iteration arrive via ONE
// coalesced vector load (lane l gets element l of the 2-row stretch) and are
// broadcast with v_readlane -> no scalar-memory serialization. 8 independent
// FMA chains + 2 independent x-gathers. One plain store per node.
// ===========================================================================
__global__ __launch_bounds__(256) void edge_csr_kernel(
    const float* __restrict__ x,      // [N,64] conv input
    const float* __restrict__ ea_s,   // [E,32] dst-sorted edge attrs
    const int*   __restrict__ src_s,  // [E] src sorted by dst
    const int*   __restrict__ rowend, // [N] inclusive ends
    const float* __restrict__ We,     // [32,64]
    const float* __restrict__ be,     // [64]
    float*       __restrict__ aggr)   // [N,64]
{
    const int lane = threadIdx.x & 63;
    const int wid  = (blockIdx.x * blockDim.x + threadIdx.x) >> 6;
    const int n0   = __builtin_amdgcn_readfirstlane(wid * NPW);
    if (n0 >= N_NODES) return;
    const int n1 = min(n0 + NPW, N_NODES);

    float w[32];
#pragma unroll
    for (int k = 0; k < 32; ++k) w[k] = We[k * 64 + lane];
    float b = be[lane];
#pragma unroll
    for (int k = 0; k < 32; ++k) asm volatile("" : "+v"(w[k]));
    asm volatile("" : "+v"(b));

    int p = (n0 == 0) ? 0 : rowend[n0 - 1];
    for (int n = n0; n < n1; ++n) {
        const int pe = rowend[n];
        float acc = 0.0f;
        // ---- 2-edge body: one coalesced 256B vector load covers both rows
        for (; p + 2 <= pe; p += 2) {
            const float ev  = ea_s[(size_t)p * 32 + lane];  // rows p, p+1
            const int s0 = src_s[p];
            const int s1 = src_s[p + 1];
            const float xv0 = x[(size_t)s0 * 64 + lane];
            const float xv1 = x[(size_t)s1 * 64 + lane];
            float a0 = b, a1 = 0.f, a2 = 0.f, a3 = 0.f;
            float c0 = b, c1 = 0.f, c2 = 0.f, c3 = 0.f;
#pragma unroll
            for (int k = 0; k < 32; k += 4) {
                a0 = fmaf(rl(ev, k+0),    w[k+0], a0);
                a1 = fmaf(rl(ev, k+1),    w[k+1], a1);
                a2 = fmaf(rl(ev, k+2),    w[k+2], a2);
                a3 = fmaf(rl(ev, k+3),    w[k+3], a3);
                c0 = fmaf(rl(ev, 32+k+0), w[k+0], c0);
                c1 = fmaf(rl(ev, 32+k+1), w[k+1], c1);
                c2 = fmaf(rl(ev, 32+k+2), w[k+2], c2);
                c3 = fmaf(rl(ev, 32+k+3), w[k+3], c3);
            }
            acc += fmaxf(xv0 + ((a0 + a1) + (a2 + a3)), 0.0f)
                 + fmaxf(xv1 + ((c0 + c1) + (c2 + c3)), 0.0f);
        }
        // ---- odd tail edge: all lanes load row p (lane&31)
        if (p < pe) {
            const float ev = ea_s[(size_t)p * 32 + (lane & 31)];
            const int s = src_s[p];
            const float xv = x[(size_t)s * 64 + lane];
            float a0 = b, a1 = 0.f, a2 = 0.f, a3 = 0.f;
#pragma unroll
            for (int k = 0; k < 32; k += 4) {
                a0 = fmaf(rl(ev, k+0), w[k+0], a0);
                a1 = fmaf(rl(ev, k+1), w[k+1], a1);
                a2 = fmaf(rl(ev, k+2), w[k+2], a2);
                a3 = fmaf(rl(ev, k+3), w[k+3], a3);
            }
            acc += fmaxf(xv + ((a0 + a1) + (a2 + a3)), 0.0f);
            ++p;
        }
        aggr[(size_t)n * 64 + lane] = acc;   // sole writer
    }
}

// ===========================================================================
// Node phase: wave per node, lane i owns feature i; readlane broadcasts,
// 4 independent FMA chains per layer.
//   out = relu( relu(((1+eps)x+aggr)@W1+b1) @ W2 + b2 )
// ===========================================================================
__global__ __launch_bounds__(256) void node_kernel(
    const float* __restrict__ x_in, const float* __restrict__ aggr,
    const float* __restrict__ eps,
    const float* __restrict__ W1, const float* __restrict__ b1,
    const float* __restrict__ W2, const float* __restrict__ b2,
    float* __restrict__ h_out)
{
    const int lane = threadIdx.x & 63;
    const int wid  = (blockIdx.x * blockDim.x + threadIdx.x) >> 6;
    const int nw   = (gridDim.x * blockDim.x) >> 6;

    float w1[64], w2[64];
#pragma unroll
    for (int i = 0; i < 64; ++i) w1[i] = W1[i * 64 + lane];
#pragma unroll
    for (int i = 0; i < 64; ++i) w2[i] = W2[i * 64 + lane];
#pragma unroll
    for (int i = 0; i < 64; ++i) asm volatile("" : "+v"(w1[i]));
#pragma unroll
    for (int i = 0; i < 64; ++i) asm volatile("" : "+v"(w2[i]));
    const float b1v = b1[lane];
    const float b2v = b2[lane];
    const float ep  = 1.0f + eps[0];

    for (int n = wid; n < N_NODES; n += nw) {
        const size_t base = (size_t)n * 64;
        const float h = fmaf(ep, x_in[base + lane], aggr[base + lane]);

        float t0 = b1v, t1 = 0.f, t2 = 0.f, t3 = 0.f;
#pragma unroll
        for (int i = 0; i < 64; i += 4) {
            t0 = fmaf(rl(h, i+0), w1[i+0], t0);
            t1 = fmaf(rl(h, i+1), w1[i+1], t1);
            t2 = fmaf(rl(h, i+2), w1[i+2], t2);
            t3 = fmaf(rl(h, i+3), w1[i+3], t3);
        }
        const float t = fmaxf((t0 + t1) + (t2 + t3), 0.0f);

        float o0 = b2v, o1 = 0.f, o2 = 0.f, o3 = 0.f;
#pragma unroll
        for (int i = 0; i < 64; i += 4) {
            o0 = fmaf(rl(t, i+0), w2[i+0], o0);
            o1 = fmaf(rl(t, i+1), w2[i+1], o1);
            o2 = fmaf(rl(t, i+2), w2[i+2], o2);
            o3 = fmaf(rl(t, i+3), w2[i+3], o3);
        }
        h_out[base + lane] = fmaxf((o0 + o1) + (o2 + o3), 0.0f);
    }
}

// ===========================================================================
// Pooling (batch sorted): wave per 16-node chunk, atomic per graph-run.
// ===========================================================================
#define POOL_CHUNK 16
__global__ __launch_bounds__(256) void pool_kernel(
    const float* __restrict__ h, const int* __restrict__ batch,
    float* __restrict__ pooled)
{
    const int lane  = threadIdx.x & 63;
    const int wid   = (blockIdx.x * blockDim.x + threadIdx.x) >> 6;
    const int start = wid * POOL_CHUNK;
    if (start >= N_NODES) return;
    const int end = min(start + POOL_CHUNK, N_NODES);

    int   gcur = batch[start];
    float acc  = 0.0f;
    for (int n = start; n < end; ++n) {
        const int g = batch[n];
        if (g != gcur) {
            atomicAdd(&pooled[gcur * 64 + lane], acc);
            acc  = 0.0f;
            gcur = g;
        }
        acc += h[(size_t)n * 64 + lane];
    }
    atomicAdd(&pooled[gcur * 64 + lane], acc);
}

// ===========================================================================
// Head: one block (128 threads) per graph.
// ===========================================================================
__global__ __launch_bounds__(128) void head_kernel(
    const float* __restrict__ pooled, const float* __restrict__ Wf1,
    const float* __restrict__ bf1, const float* __restrict__ Wf2,
    const float* __restrict__ bf2, float* __restrict__ out)
{
    __shared__ float p[64];
    __shared__ float red[2];
    const int g = blockIdx.x;
    const int j = threadIdx.x;

    if (j < 64) p[j] = pooled[g * 64 + j];
    __syncthreads();

    float t = bf1[j];
#pragma unroll
    for (int i = 0; i < 64; ++i)
        t = fmaf(p[i], Wf1[i * 128 + j], t);
    t = fmaxf(t, 0.0f);

    float v = t * Wf2[j];
    for (int off = 32; off > 0; off >>= 1)
        v += __shfl_down(v, off);
    if ((j & 63) == 0) red[j >> 6] = v;
    __syncthreads();
    if (j == 0) out[g] = red[0] + red[1] + bf2[0];
}

extern "C" void kernel_launch(void* const* d_in, const int* in_sizes, int n_in,
                              void* d_out, int out_size, void* d_ws, size_t ws_size,
                              hipStream_t stream) {
    const float* x    = (const float*)d_in[0];
    const float* ea   = (const float*)d_in[1];
    const int*   esrc = (const int*)  d_in[2];
    const int*   edst = (const int*)  d_in[3];
    const int*   batch= (const int*)  d_in[4];
    const float* eps1 = (const float*)d_in[5];
    const float* We1  = (const float*)d_in[6];
    const float* be1  = (const float*)d_in[7];
    const float* W11  = (const float*)d_in[8];
    const float* b11  = (const float*)d_in[9];
    const float* W12  = (const float*)d_in[10];
    const float* b12  = (const float*)d_in[11];
    const float* eps2 = (const float*)d_in[12];
    const float* We2  = (const float*)d_in[13];
    const float* be2  = (const float*)d_in[14];
    const float* W21  = (const float*)d_in[15];
    const float* b21  = (const float*)d_in[16];
    const float* W22  = (const float*)d_in[17];
    const float* b22  = (const float*)d_in[18];
    const float* Wf1  = (const float*)d_in[19];
    const float* bf1  = (const float*)d_in[20];
    const float* Wf2  = (const float*)d_in[21];
    const float* bf2  = (const float*)d_in[22];
    float* out = (float*)d_out;

    // ---- workspace layout ----
    const size_t NF = (size_t)N_NODES * 64 * sizeof(float);  // 25,600,000
    char* ws = (char*)d_ws;
    float* aggr   = (float*)ws;                        // 25.6 MB
    float* h      = (float*)(ws + NF);                 // 25.6 MB
    float* pooled = (float*)(ws + 2 * NF);             // 32 KB
    char*  p4     = ws + 2 * NF + 32768;
    int* counts = (int*)p4;                            // 409,600 B
    int* cursor = (int*)(p4 + 409600);                 // 409,600 B (-> rowend)
    int* src_s  = (int*)(p4 + 2 * 409600);             // 4,000,000 B
    int* bsum   = (int*)(p4 + 2 * 409600 + 4000000);   // 512 B
    int* boff   = (int*)(p4 + 2 * 409600 + 4000512);   // 512 B
    char*  p5   = p4 + 2 * 409600 + 4001024;
    float* ea_s = (float*)p5;                          // 128,000,000 B
    // pos_s lives in aggr's space: only used before conv1's edge kernel,
    // which overwrites every aggr element. No extra ws needed.
    int* pos_s  = (int*)aggr;                          // 4,000,000 B (aliased)

    const int E_TH_BLOCKS  = (N_EDGES + 255) / 256;                 // 3907
    const int PERM_BLOCKS  = (N_EDGES / 8 + 3) / 4;                 // 31250
    const int EDGE_WAVES   = (N_NODES + NPW - 1) / NPW;             // 25000
    const int EDGE_BLOCKS  = (EDGE_WAVES + 3) / 4;                  // 6250
    const int NODE_BLOCKS  = 1024;
    const int POOL_BLOCKS  = ((N_NODES + POOL_CHUNK - 1) / POOL_CHUNK + 3) / 4;

    // ---- CSR build: counts -> 3-stage scan -> pos-assign -> data move ----
    hipMemsetAsync(counts, 0, 409600, stream);
    count_kernel<<<E_TH_BLOCKS, 256, 0, stream>>>(edst, counts);
    scan1_kernel<<<SCAN_NB, SCAN_BLK, 0, stream>>>(counts, cursor, bsum);
    scan2_kernel<<<1, 128, 0, stream>>>(bsum, boff);
    scan3_kernel<<<SCAN_NB, SCAN_BLK, 0, stream>>>(cursor, boff);
    pos_kernel<<<E_TH_BLOCKS, 256, 0, stream>>>(esrc, edst, cursor, pos_s, src_s);
    perm_kernel<<<PERM_BLOCKS, 256, 0, stream>>>(ea, pos_s, ea_s);

    // ---- conv1 ----
    edge_csr_kernel<<<EDGE_BLOCKS, 256, 0, stream>>>(
        x, ea_s, src_s, cursor, We1, be1, aggr);
    node_kernel<<<NODE_BLOCKS, 256, 0, stream>>>(x, aggr, eps1, W11, b11, W12, b12, h);

    // ---- conv2 ----
    edge_csr_kernel<<<EDGE_BLOCKS, 256, 0, stream>>>(
        h, ea_s, src_s, cursor, We2, be2, aggr);
    node_kernel<<<NODE_BLOCKS, 256, 0, stream>>>(h, aggr, eps2, W21, b21, W22, b22, h);

    // ---- global_add_pool + head ----
    hipMemsetAsync(pooled, 0, (size_t)N_GRAPHS * 64 * sizeof(float), stream);
    pool_kernel<<<POOL_BLOCKS, 256, 0, stream>>>(h, batch, pooled);
    head_kernel<<<N_GRAPHS, 128, 0, stream>>>(pooled, Wf1, bf1, Wf2, bf2, out);
}

// Round 9
// 667.102 us; speedup vs baseline: 2.0783x; 1.0655x over previous
//
#include <hip/hip_runtime.h>

#define N_NODES 100000
#define N_EDGES 1000000
#define N_GRAPHS 128
#define NPW 4            // dst nodes per wave in edge phase
#define TILE_E 32        // edges staged in LDS per wave
#define SCAN_BLK 1024
#define SCAN_NB ((N_NODES + SCAN_BLK - 1) / SCAN_BLK)   // 98

typedef float v2f __attribute__((ext_vector_type(2)));
typedef float v4f __attribute__((ext_vector_type(4)));

// packed dual fp32 FMA: d = a*b + c on both halves (VOP3P, CDNA2+)
__device__ __forceinline__ v2f pk_fma(v2f a, v2f b, v2f c) {
    v2f d;
    asm("v_pk_fma_f32 %0, %1, %2, %3" : "=v"(d) : "v"(a), "v"(b), "v"(c));
    return d;
}

// ===========================================================================
// Counting-sort of edges by dst -> CSR (+ permuted edge attrs).
// ===========================================================================
__global__ __launch_bounds__(256) void count_kernel(
    const int* __restrict__ dst, int* __restrict__ counts)
{
    int e = blockIdx.x * blockDim.x + threadIdx.x;
    if (e < N_EDGES) atomicAdd(&counts[dst[e]], 1);
}

__global__ __launch_bounds__(SCAN_BLK) void scan1_kernel(
    const int* __restrict__ counts, int* __restrict__ cursor,
    int* __restrict__ bsum)
{
    __shared__ int sm[SCAN_BLK];
    const int t = threadIdx.x;
    const int i = blockIdx.x * SCAN_BLK + t;
    const int v = (i < N_NODES) ? counts[i] : 0;
    sm[t] = v;
    __syncthreads();
    for (int off = 1; off < SCAN_BLK; off <<= 1) {
        int tmp = (t >= off) ? sm[t - off] : 0;
        __syncthreads();
        sm[t] += tmp;
        __syncthreads();
    }
    if (i < N_NODES) cursor[i] = sm[t] - v;
    if (t == SCAN_BLK - 1) bsum[blockIdx.x] = sm[t];
}

__global__ __launch_bounds__(128) void scan2_kernel(
    const int* __restrict__ bsum, int* __restrict__ boff)
{
    __shared__ int sm[128];
    const int t = threadIdx.x;
    const int v = (t < SCAN_NB) ? bsum[t] : 0;
    sm[t] = v;
    __syncthreads();
    for (int off = 1; off < 128; off <<= 1) {
        int tmp = (t >= off) ? sm[t - off] : 0;
        __syncthreads();
        sm[t] += tmp;
        __syncthreads();
    }
    if (t < SCAN_NB) boff[t] = sm[t] - v;
}

__global__ __launch_bounds__(SCAN_BLK) void scan3_kernel(
    int* __restrict__ cursor, const int* __restrict__ boff)
{
    const int i = blockIdx.x * SCAN_BLK + threadIdx.x;
    if (i < N_NODES) cursor[i] += boff[blockIdx.x];
}

// ---------------------------------------------------------------------------
// Scatter pass 1: position assignment (atomic); cursor ends as INCLUSIVE end.
// ---------------------------------------------------------------------------
__global__ __launch_bounds__(256) void pos_kernel(
    const int* __restrict__ src, const int* __restrict__ dst,
    int* __restrict__ cursor,
    int* __restrict__ pos_s, int* __restrict__ src_s)
{
    int e = blockIdx.x * blockDim.x + threadIdx.x;
    if (e >= N_EDGES) return;
    int p = atomicAdd(&cursor[dst[e]], 1);
    pos_s[e] = p;
    src_s[p] = src[e];
}

// ---------------------------------------------------------------------------
// Scatter pass 2: pure data move, 8 edges per wave, no atomic dependency.
// ---------------------------------------------------------------------------
__global__ __launch_bounds__(256) void perm_kernel(
    const float* __restrict__ ea, const int* __restrict__ pos_s,
    float* __restrict__ ea_s)
{
    const int lane  = threadIdx.x & 63;
    const int wid   = (blockIdx.x * blockDim.x + threadIdx.x) >> 6;
    const int r     = lane >> 3;      // row within wave, 0..7
    const int q     = lane & 7;       // 16B chunk within row, 0..7
    const int ebase = wid * 8;
    if (ebase >= N_EDGES) return;

    const int mypos = pos_s[ebase + r];
    const float4 v = *(const float4*)(ea + (size_t)(ebase + r) * 32 + q * 4);
    *(float4*)(ea_s + (size_t)mypos * 32 + q * 4) = v;
}

// ===========================================================================
// Edge phase: wave per NPW consecutive dst nodes, lane i = feature i.
// Wave's contiguous edge slice is staged through a wave-PRIVATE LDS buffer
// (no barriers needed); edge-attr values are broadcast to all lanes via
// uniform-address ds_read_b128 (DS pipe, off-VALU), and the 32-term dot
// product runs as 16 v_pk_fma_f32 on 4 independent chains. One plain store
// per node (zero-degree included -> no memset, no atomics).
// ===========================================================================
__global__ __launch_bounds__(256) void edge_csr_kernel(
    const float* __restrict__ x,      // [N,64] conv input
    const float* __restrict__ ea_s,   // [E,32] dst-sorted edge attrs
    const int*   __restrict__ src_s,  // [E] src sorted by dst
    const int*   __restrict__ rowend, // [N] inclusive ends
    const float* __restrict__ We,     // [32,64]
    const float* __restrict__ be,     // [64]
    float*       __restrict__ aggr)   // [N,64]
{
    __shared__ float smem[4][TILE_E * 32];   // 4 waves x 4KB
    const int lane  = threadIdx.x & 63;
    const int wslot = threadIdx.x >> 6;
    const int wid   = (blockIdx.x * blockDim.x + threadIdx.x) >> 6;
    const int n0    = __builtin_amdgcn_readfirstlane(wid * NPW);
    if (n0 >= N_NODES) return;
    const int n1 = min(n0 + NPW, N_NODES);

    // per-lane weight column as 16 pairs, pinned in VGPRs
    v2f w2[16];
#pragma unroll
    for (int k = 0; k < 16; ++k)
        w2[k] = (v2f){We[(2 * k) * 64 + lane], We[(2 * k + 1) * 64 + lane]};
    float b = be[lane];
#pragma unroll
    for (int k = 0; k < 16; ++k) asm volatile("" : "+v"(w2[k]));
    asm volatile("" : "+v"(b));

    v4f* buf4 = (v4f*)smem[wslot];

    int p = (n0 == 0) ? 0 : rowend[n0 - 1];
    const int pend = rowend[n1 - 1];
    int bufpos = TILE_E;                      // force initial stage

    for (int n = n0; n < n1; ++n) {
        const int pe = rowend[n];
        float acc = 0.0f;
        for (; p < pe; ++p) {
            if (bufpos == TILE_E) {           // uniform branch: restage
                const int tn8 = min(TILE_E, pend - p) * 8;   // float4 count
                const v4f* g4 = (const v4f*)(ea_s + (size_t)p * 32);
                if (tn8 == TILE_E * 8) {
                    // full tile: issue all 4 loads, then all 4 writes
                    v4f a0 = g4[lane], a1 = g4[lane + 64],
                        a2 = g4[lane + 128], a3 = g4[lane + 192];
                    buf4[lane] = a0;       buf4[lane + 64] = a1;
                    buf4[lane + 128] = a2; buf4[lane + 192] = a3;
                } else {
                    for (int j = lane; j < tn8; j += 64) buf4[j] = g4[j];
                }
                bufpos = 0;
            }
            const int s = src_s[p];                      // uniform s_load
            const float xv = x[(size_t)s * 64 + lane];   // the one gather

            v2f e0 = {0.f, 0.f}, e1 = {0.f, 0.f},
                e2 = {0.f, 0.f}, e3 = {0.f, 0.f};
            const int bo8 = bufpos * 8;
#pragma unroll
            for (int j = 0; j < 8; j += 2) {
                const v4f qa = buf4[bo8 + j];       // uniform-addr b128 bcast
                const v4f qb = buf4[bo8 + j + 1];
                e0 = pk_fma(qa.xy, w2[2 * j + 0], e0);
                e1 = pk_fma(qa.zw, w2[2 * j + 1], e1);
                e2 = pk_fma(qb.xy, w2[2 * j + 2], e2);
                e3 = pk_fma(qb.zw, w2[2 * j + 3], e3);
            }
            const v2f es = (e0 + e1) + (e2 + e3);
            acc += fmaxf(xv + (es.x + es.y + b), 0.0f);
            ++bufpos;
        }
        aggr[(size_t)n * 64 + lane] = acc;               // sole writer
    }
}

// ===========================================================================
// Node phase: wave per node, lane i owns feature i. h / t are staged through
// wave-private LDS and broadcast back via uniform ds_read_b128; each 64-term
// dot is 32 pk_fma on 4 chains.
//   out = relu( relu(((1+eps)x+aggr)@W1+b1) @ W2 + b2 )
// ===========================================================================
__global__ __launch_bounds__(256) void node_kernel(
    const float* __restrict__ x_in, const float* __restrict__ aggr,
    const float* __restrict__ eps,
    const float* __restrict__ W1, const float* __restrict__ b1,
    const float* __restrict__ W2, const float* __restrict__ b2,
    float* __restrict__ h_out)
{
    __shared__ float hsm[4][64];
    __shared__ float tsm[4][64];
    const int lane  = threadIdx.x & 63;
    const int wslot = threadIdx.x >> 6;
    const int wid   = (blockIdx.x * blockDim.x + threadIdx.x) >> 6;
    const int nw    = (gridDim.x * blockDim.x) >> 6;

    v2f w1p[32], w2p[32];
#pragma unroll
    for (int j = 0; j < 32; ++j)
        w1p[j] = (v2f){W1[(2 * j) * 64 + lane], W1[(2 * j + 1) * 64 + lane]};
#pragma unroll
    for (int j = 0; j < 32; ++j)
        w2p[j] = (v2f){W2[(2 * j) * 64 + lane], W2[(2 * j + 1) * 64 + lane]};
#pragma unroll
    for (int j = 0; j < 32; ++j) asm volatile("" : "+v"(w1p[j]));
#pragma unroll
    for (int j = 0; j < 32; ++j) asm volatile("" : "+v"(w2p[j]));
    const float b1v = b1[lane];
    const float b2v = b2[lane];
    const float ep  = 1.0f + eps[0];

    const v4f* hv = (const v4f*)hsm[wslot];
    const v4f* tv = (const v4f*)tsm[wslot];

    for (int n = wid; n < N_NODES; n += nw) {
        const size_t base = (size_t)n * 64;
        const float h = fmaf(ep, x_in[base + lane], aggr[base + lane]);
        hsm[wslot][lane] = h;                 // ds_write, same-wave visible

        v2f t0 = {0.f, 0.f}, t1 = {0.f, 0.f}, t2 = {0.f, 0.f}, t3 = {0.f, 0.f};
#pragma unroll
        for (int j = 0; j < 16; j += 2) {
            const v4f qa = hv[j];
            const v4f qb = hv[j + 1];
            t0 = pk_fma(qa.xy, w1p[2 * j + 0], t0);
            t1 = pk_fma(qa.zw, w1p[2 * j + 1], t1);
            t2 = pk_fma(qb.xy, w1p[2 * j + 2], t2);
            t3 = pk_fma(qb.zw, w1p[2 * j + 3], t3);
        }
        const v2f tsum = (t0 + t1) + (t2 + t3);
        const float t = fmaxf(tsum.x + tsum.y + b1v, 0.0f);
        tsm[wslot][lane] = t;

        v2f o0 = {0.f, 0.f}, o1 = {0.f, 0.f}, o2 = {0.f, 0.f}, o3 = {0.f, 0.f};
#pragma unroll
        for (int j = 0; j < 16; j += 2) {
            const v4f qa = tv[j];
            const v4f qb = tv[j + 1];
            o0 = pk_fma(qa.xy, w2p[2 * j + 0], o0);
            o1 = pk_fma(qa.zw, w2p[2 * j + 1], o1);
            o2 = pk_fma(qb.xy, w2p[2 * j + 2], o2);
            o3 = pk_fma(qb.zw, w2p[2 * j + 3], o3);
        }
        const v2f osum = (o0 + o1) + (o2 + o3);
        h_out[base + lane] = fmaxf(osum.x + osum.y + b2v, 0.0f);
    }
}

// ===========================================================================
// Pooling (batch sorted): wave per 16-node chunk, atomic per graph-run.
// ===========================================================================
#define POOL_CHUNK 16
__global__ __launch_bounds__(256) void pool_kernel(
    const float* __restrict__ h, const int* __restrict__ batch,
    float* __restrict__ pooled)
{
    const int lane  = threadIdx.x & 63;
    const int wid   = (blockIdx.x * blockDim.x + threadIdx.x) >> 6;
    const int start = wid * POOL_CHUNK;
    if (start >= N_NODES) return;
    const int end = min(start + POOL_CHUNK, N_NODES);

    int   gcur = batch[start];
    float acc  = 0.0f;
    for (int n = start; n < end; ++n) {
        const int g = batch[n];
        if (g != gcur) {
            atomicAdd(&pooled[gcur * 64 + lane], acc);
            acc  = 0.0f;
            gcur = g;
        }
        acc += h[(size_t)n * 64 + lane];
    }
    atomicAdd(&pooled[gcur * 64 + lane], acc);
}

// ===========================================================================
// Head: one block (128 threads) per graph.
// ===========================================================================
__global__ __launch_bounds__(128) void head_kernel(
    const float* __restrict__ pooled, const float* __restrict__ Wf1,
    const float* __restrict__ bf1, const float* __restrict__ Wf2,
    const float* __restrict__ bf2, float* __restrict__ out)
{
    __shared__ float p[64];
    __shared__ float red[2];
    const int g = blockIdx.x;
    const int j = threadIdx.x;

    if (j < 64) p[j] = pooled[g * 64 + j];
    __syncthreads();

    float t = bf1[j];
#pragma unroll
    for (int i = 0; i < 64; ++i)
        t = fmaf(p[i], Wf1[i * 128 + j], t);
    t = fmaxf(t, 0.0f);

    float v = t * Wf2[j];
    for (int off = 32; off > 0; off >>= 1)
        v += __shfl_down(v, off);
    if ((j & 63) == 0) red[j >> 6] = v;
    __syncthreads();
    if (j == 0) out[g] = red[0] + red[1] + bf2[0];
}

extern "C" void kernel_launch(void* const* d_in, const int* in_sizes, int n_in,
                              void* d_out, int out_size, void* d_ws, size_t ws_size,
                              hipStream_t stream) {
    const float* x    = (const float*)d_in[0];
    const float* ea   = (const float*)d_in[1];
    const int*   esrc = (const int*)  d_in[2];
    const int*   edst = (const int*)  d_in[3];
    const int*   batch= (const int*)  d_in[4];
    const float* eps1 = (const float*)d_in[5];
    const float* We1  = (const float*)d_in[6];
    const float* be1  = (const float*)d_in[7];
    const float* W11  = (const float*)d_in[8];
    const float* b11  = (const float*)d_in[9];
    const float* W12  = (const float*)d_in[10];
    const float* b12  = (const float*)d_in[11];
    const float* eps2 = (const float*)d_in[12];
    const float* We2  = (const float*)d_in[13];
    const float* be2  = (const float*)d_in[14];
    const float* W21  = (const float*)d_in[15];
    const float* b21  = (const float*)d_in[16];
    const float* W22  = (const float*)d_in[17];
    const float* b22  = (const float*)d_in[18];
    const float* Wf1  = (const float*)d_in[19];
    const float* bf1  = (const float*)d_in[20];
    const float* Wf2  = (const float*)d_in[21];
    const float* bf2  = (const float*)d_in[22];
    float* out = (float*)d_out;

    // ---- workspace layout ----
    const size_t NF = (size_t)N_NODES * 64 * sizeof(float);  // 25,600,000
    char* ws = (char*)d_ws;
    float* aggr   = (float*)ws;                        // 25.6 MB
    float* h      = (float*)(ws + NF);                 // 25.6 MB
    float* pooled = (float*)(ws + 2 * NF);             // 32 KB
    char*  p4     = ws + 2 * NF + 32768;
    int* counts = (int*)p4;                            // 409,600 B
    int* cursor = (int*)(p4 + 409600);                 // 409,600 B (-> rowend)
    int* src_s  = (int*)(p4 + 2 * 409600);             // 4,000,000 B
    int* bsum   = (int*)(p4 + 2 * 409600 + 4000000);   // 512 B
    int* boff   = (int*)(p4 + 2 * 409600 + 4000512);   // 512 B
    char*  p5   = p4 + 2 * 409600 + 4001024;
    float* ea_s = (float*)p5;                          // 128,000,000 B
    // pos_s aliases aggr: consumed by perm_kernel before conv1's edge kernel
    // overwrites every aggr element.
    int* pos_s  = (int*)aggr;

    const int E_TH_BLOCKS  = (N_EDGES + 255) / 256;                 // 3907
    const int PERM_BLOCKS  = (N_EDGES / 8 + 3) / 4;                 // 31250
    const int EDGE_WAVES   = (N_NODES + NPW - 1) / NPW;             // 25000
    const int EDGE_BLOCKS  = (EDGE_WAVES + 3) / 4;                  // 6250
    const int NODE_BLOCKS  = 1024;
    const int POOL_BLOCKS  = ((N_NODES + POOL_CHUNK - 1) / POOL_CHUNK + 3) / 4;

    // ---- CSR build: counts -> 3-stage scan -> pos-assign -> data move ----
    hipMemsetAsync(counts, 0, 409600, stream);
    count_kernel<<<E_TH_BLOCKS, 256, 0, stream>>>(edst, counts);
    scan1_kernel<<<SCAN_NB, SCAN_BLK, 0, stream>>>(counts, cursor, bsum);
    scan2_kernel<<<1, 128, 0, stream>>>(bsum, boff);
    scan3_kernel<<<SCAN_NB, SCAN_BLK, 0, stream>>>(cursor, boff);
    pos_kernel<<<E_TH_BLOCKS, 256, 0, stream>>>(esrc, edst, cursor, pos_s, src_s);
    perm_kernel<<<PERM_BLOCKS, 256, 0, stream>>>(ea, pos_s, ea_s);

    // ---- conv1 ----
    edge_csr_kernel<<<EDGE_BLOCKS, 256, 0, stream>>>(
        x, ea_s, src_s, cursor, We1, be1, aggr);
    node_kernel<<<NODE_BLOCKS, 256, 0, stream>>>(x, aggr, eps1, W11, b11, W12, b12, h);

    // ---- conv2 ----
    edge_csr_kernel<<<EDGE_BLOCKS, 256, 0, stream>>>(
        h, ea_s, src_s, cursor, We2, be2, aggr);
    node_kernel<<<NODE_BLOCKS, 256, 0, stream>>>(h, aggr, eps2, W21, b21, W22, b22, h);

    // ---- global_add_pool + head ----
    hipMemsetAsync(pooled, 0, (size_t)N_GRAPHS * 64 * sizeof(float), stream);
    pool_kernel<<<POOL_BLOCKS, 256, 0, stream>>>(h, batch, pooled);
    head_kernel<<<N_GRAPHS, 128, 0, stream>>>(pooled, Wf1, bf1, Wf2, bf2, out);
}